// Round 1
// baseline (22921.230 us; speedup 1.0000x reference)
//
#include <hip/hip_runtime.h>
#include <hip/hip_bf16.h>
#include <math.h>

#define EPS 1e-5f
#define SLOPE 0.2f

// ---------------------------------------------------------------------------
// Layer geometry (all strided 4x4, stride 2, pad 1):
//  L1: [512,  1,48,80] -> [512, 64,24,40]
//  L2: [512, 64,24,40] -> [512,128,12,20]
//  L3: [512,128,12,20] -> [512,256, 6,10]
//  L4: [512,256, 6,10] -> [512,512, 3, 5]
// Intermediates stored NHWC (channel innermost) for contiguous dot products.
// BN training-mode stats via deterministic two-stage reduction, then in-place
// normalize+LeakyReLU; head gathers per-sample expert weights.
// ---------------------------------------------------------------------------

// ---- weight transpose: OIHW -> [co][kh*4+kw][ci] ----
__global__ __launch_bounds__(256) void twk(const float* __restrict__ W,
                                           float* __restrict__ wT, int O, int I) {
    int idx = blockIdx.x * 256 + threadIdx.x;
    int total = O * I * 16;
    if (idx >= total) return;
    int k = idx & 15;
    int rest = idx >> 4;
    int ci = rest % I;
    int co = rest / I;
    wT[((size_t)co * 16 + k) * I + ci] = W[idx];
}

// ---- conv1: C_in = 1 (NCHW input == NHWC), writes h1 NHWC [n][oh][ow][64] ----
__global__ __launch_bounds__(256) void conv1_k(const float* __restrict__ x,
                                               const float* __restrict__ W1,
                                               float* __restrict__ out) {
    int idx = blockIdx.x * 256 + threadIdx.x;
    int co = idx & 63;
    int rest = idx >> 6;
    int ow = rest % 40; rest /= 40;
    int oh = rest % 24;
    int n  = rest / 24;
    const float4* wr = (const float4*)(W1 + co * 16);
    float4 wa = wr[0], wb = wr[1], wc = wr[2], wd = wr[3];
    float wk[16] = {wa.x, wa.y, wa.z, wa.w, wb.x, wb.y, wb.z, wb.w,
                    wc.x, wc.y, wc.z, wc.w, wd.x, wd.y, wd.z, wd.w};
    float acc = 0.f;
#pragma unroll
    for (int kh = 0; kh < 4; ++kh) {
        int ih = oh * 2 - 1 + kh;
        if ((unsigned)ih >= 48u) continue;
        const float* xr = x + ((size_t)n * 48 + ih) * 80;
#pragma unroll
        for (int kw = 0; kw < 4; ++kw) {
            int iw = ow * 2 - 1 + kw;
            if ((unsigned)iw >= 80u) continue;
            acc = fmaf(xr[iw], wk[kh * 4 + kw], acc);
        }
    }
    out[idx] = acc;
}

// ---- generic NHWC conv, k=4 s=2 p=1; input already BN+LReLU'd in place ----
template<int CIN, int COUT, int IH, int IW, int OH, int OW>
__global__ __launch_bounds__(256) void convN_k(const float* __restrict__ in,
                                               const float* __restrict__ wT,
                                               float* __restrict__ out) {
    int idx = blockIdx.x * 256 + threadIdx.x;
    int co = idx & (COUT - 1);
    int rest = idx / COUT;
    int ow = rest % OW; rest /= OW;
    int oh = rest % OH;
    int n  = rest / OH;
    const float4* w4 = (const float4*)(wT + (size_t)co * 16 * CIN);
    float acc = 0.f;
#pragma unroll
    for (int kh = 0; kh < 4; ++kh) {
        int ih = oh * 2 - 1 + kh;
        if ((unsigned)ih >= (unsigned)IH) continue;
#pragma unroll
        for (int kw = 0; kw < 4; ++kw) {
            int iw = ow * 2 - 1 + kw;
            if ((unsigned)iw >= (unsigned)IW) continue;
            const float4* a4 = (const float4*)(in + (((size_t)n * IH + ih) * IW + iw) * CIN);
            const float4* b4 = w4 + (kh * 4 + kw) * (CIN / 4);
#pragma unroll 8
            for (int i = 0; i < CIN / 4; ++i) {
                float4 a = a4[i];
                float4 b = b4[i];
                acc = fmaf(a.x, b.x, acc);
                acc = fmaf(a.y, b.y, acc);
                acc = fmaf(a.z, b.z, acc);
                acc = fmaf(a.w, b.w, acc);
            }
        }
    }
    out[idx] = acc;
}

// ---- BN stats stage 1: per-block partial sum/sumsq per channel (deterministic) ----
template<int C>
__global__ __launch_bounds__(256) void reduce1_k(const float* __restrict__ h,
                                                 float* __restrict__ part,
                                                 int R, int rpb) {
    int t = threadIdx.x;
    int bid = blockIdx.x;
    int r_lo = bid * rpb;
    int r_hi = min(R, r_lo + rpb);
    if constexpr (C <= 256) {
        constexpr int STEP = 256 / C;
        int c = t & (C - 1);
        float s = 0.f, q = 0.f;
        for (int r = r_lo + (t / C); r < r_hi; r += STEP) {
            float v = h[(size_t)r * C + c];
            s += v; q += v * v;
        }
        __shared__ float ls[256], lq[256];
        ls[t] = s; lq[t] = q; __syncthreads();
        for (int d = 128; d >= C; d >>= 1) {
            if (t < d) { ls[t] += ls[t + d]; lq[t] += lq[t + d]; }
            __syncthreads();
        }
        if (t < C) {
            part[(size_t)bid * 2 * C + t]     = ls[t];
            part[(size_t)bid * 2 * C + C + t] = lq[t];
        }
    } else {  // C == 512: two channels per thread
        float s0 = 0.f, q0 = 0.f, s1 = 0.f, q1 = 0.f;
        for (int r = r_lo; r < r_hi; ++r) {
            float v0 = h[(size_t)r * C + t];
            float v1 = h[(size_t)r * C + t + 256];
            s0 += v0; q0 += v0 * v0;
            s1 += v1; q1 += v1 * v1;
        }
        part[(size_t)bid * 2 * C + t]           = s0;
        part[(size_t)bid * 2 * C + t + 256]     = s1;
        part[(size_t)bid * 2 * C + C + t]       = q0;
        part[(size_t)bid * 2 * C + C + t + 256] = q1;
    }
}

// ---- BN stats stage 2: fold partials, emit scale/shift st = [s[0..C), t[0..C)] ----
template<int C>
__global__ void stats_k(const float* __restrict__ part,
                        const float* __restrict__ gamma,
                        const float* __restrict__ beta,
                        float* __restrict__ st, int nblocks, float invR) {
    int c = threadIdx.x;  // blockDim == C
    float s = 0.f, q = 0.f;
    for (int b = 0; b < nblocks; ++b) {
        s += part[(size_t)b * 2 * C + c];
        q += part[(size_t)b * 2 * C + C + c];
    }
    float mean = s * invR;
    float var  = q * invR - mean * mean;
    float sc = gamma[c] * rsqrtf(var + EPS);
    st[c]     = sc;
    st[C + c] = beta[c] - mean * sc;
}

// ---- in-place normalize + LeakyReLU (float4) ----
template<int C>
__global__ __launch_bounds__(256) void scale_k(float* __restrict__ h,
                                               const float* __restrict__ st,
                                               size_t n4) {
    size_t i = (size_t)blockIdx.x * 256 + threadIdx.x;
    size_t stride = (size_t)gridDim.x * 256;
    float4* h4 = (float4*)h;
    for (; i < n4; i += stride) {
        float4 v = h4[i];
        int c0 = (int)((i * 4) & (size_t)(C - 1));
        float s0 = st[c0],     s1 = st[c0 + 1],     s2 = st[c0 + 2],     s3 = st[c0 + 3];
        float t0 = st[C + c0], t1 = st[C + c0 + 1], t2 = st[C + c0 + 2], t3 = st[C + c0 + 3];
        v.x = fmaf(v.x, s0, t0); v.x = v.x >= 0.f ? v.x : SLOPE * v.x;
        v.y = fmaf(v.y, s1, t1); v.y = v.y >= 0.f ? v.y : SLOPE * v.y;
        v.z = fmaf(v.z, s2, t2); v.z = v.z >= 0.f ? v.z : SLOPE * v.z;
        v.w = fmaf(v.w, s3, t3); v.w = v.w >= 0.f ? v.w : SLOPE * v.w;
        h4[i] = v;
    }
}

// ---- expert head: out[b] = sum_{c,hw} h4[b,hw,c] * W5[y[b],c,hw] ----
__global__ __launch_bounds__(256) void head_k(const float* __restrict__ h4,
                                              const float* __restrict__ W5,
                                              const int* __restrict__ y,
                                              float* __restrict__ out) {
    int b = blockIdx.x;
    int t = threadIdx.x;
    int e = y[b];
    const float* w  = W5 + (size_t)e * 7680;   // [512][3][5]: c*15 + hw
    const float* hb = h4 + (size_t)b * 7680;   // NHWC: hw*512 + c
    float s = 0.f;
    for (int f = t; f < 7680; f += 256) {
        int c  = f & 511;
        int hw = f >> 9;
        s = fmaf(hb[f], w[c * 15 + hw], s);
    }
    __shared__ float ls[256];
    ls[t] = s; __syncthreads();
    for (int d = 128; d > 0; d >>= 1) {
        if (t < d) ls[t] += ls[t + d];
        __syncthreads();
    }
    if (t == 0) out[b] = ls[0];
}

extern "C" void kernel_launch(void* const* d_in, const int* in_sizes, int n_in,
                              void* d_out, int out_size, void* d_ws, size_t ws_size,
                              hipStream_t stream) {
    const float* x  = (const float*)d_in[0];
    const float* W1 = (const float*)d_in[1];
    const float* g1 = (const float*)d_in[2];
    const float* b1 = (const float*)d_in[3];
    const float* W2 = (const float*)d_in[4];
    const float* g2 = (const float*)d_in[5];
    const float* b2 = (const float*)d_in[6];
    const float* W3 = (const float*)d_in[7];
    const float* g3 = (const float*)d_in[8];
    const float* b3 = (const float*)d_in[9];
    const float* W4 = (const float*)d_in[10];
    const float* g4 = (const float*)d_in[11];
    const float* b4 = (const float*)d_in[12];
    const float* W5 = (const float*)d_in[13];
    const int*   y  = (const int*)d_in[14];
    float* out = (float*)d_out;

    // ---- workspace layout (floats), peak ~202 MB ----
    const size_t H1 = (size_t)512 * 24 * 40 * 64;    // 31,457,280
    const size_t H2 = (size_t)512 * 12 * 20 * 128;   // 15,728,640
    const size_t H3 = (size_t)512 * 6  * 10 * 256;   //  7,864,320
    const size_t H4 = (size_t)512 * 3  * 5  * 512;   //  3,932,160
    float* ws  = (float*)d_ws;
    float* h1  = ws;
    float* h2  = h1 + H1;
    float* h3  = h1;                  // reuse: h1 dead after conv2
    float* h4  = h2;                  // reuse: h2 dead after conv3
    float* wt2 = h2 + H2;             // 128*64*16   = 131072
    float* wt3 = wt2 + 131072;        // 256*128*16  = 524288
    float* wt4 = wt3 + 524288;        // 512*256*16  = 2097152
    float* part = wt4 + 2097152;      // 512 blocks * 2*512ch max = 524288
    float* st1 = part + 524288;
    float* st2 = st1 + 128;
    float* st3 = st2 + 256;
    float* st4 = st3 + 512;

    const int NB = 512;  // stage-1 reduction blocks per layer

    // weight transposes (cheap, every call — deterministic)
    twk<<<(128 * 64 * 16 + 255) / 256, 256, 0, stream>>>(W2, wt2, 128, 64);
    twk<<<(256 * 128 * 16 + 255) / 256, 256, 0, stream>>>(W3, wt3, 256, 128);
    twk<<<(512 * 256 * 16 + 255) / 256, 256, 0, stream>>>(W4, wt4, 512, 256);

    // ---- L1 ----
    conv1_k<<<(int)(H1 / 256), 256, 0, stream>>>(x, W1, h1);
    {
        int R = 512 * 24 * 40, rpb = (R + NB - 1) / NB;
        reduce1_k<64><<<NB, 256, 0, stream>>>(h1, part, R, rpb);
        stats_k<64><<<1, 64, 0, stream>>>(part, g1, b1, st1, NB, 1.f / R);
        scale_k<64><<<4096, 256, 0, stream>>>(h1, st1, H1 / 4);
    }
    // ---- L2 ----
    convN_k<64, 128, 24, 40, 12, 20><<<(int)(H2 / 256), 256, 0, stream>>>(h1, wt2, h2);
    {
        int R = 512 * 12 * 20, rpb = (R + NB - 1) / NB;
        reduce1_k<128><<<NB, 256, 0, stream>>>(h2, part, R, rpb);
        stats_k<128><<<1, 128, 0, stream>>>(part, g2, b2, st2, NB, 1.f / R);
        scale_k<128><<<4096, 256, 0, stream>>>(h2, st2, H2 / 4);
    }
    // ---- L3 ----
    convN_k<128, 256, 12, 20, 6, 10><<<(int)(H3 / 256), 256, 0, stream>>>(h2, wt3, h3);
    {
        int R = 512 * 6 * 10, rpb = (R + NB - 1) / NB;
        reduce1_k<256><<<NB, 256, 0, stream>>>(h3, part, R, rpb);
        stats_k<256><<<1, 256, 0, stream>>>(part, g3, b3, st3, NB, 1.f / R);
        scale_k<256><<<2048, 256, 0, stream>>>(h3, st3, H3 / 4);
    }
    // ---- L4 ----
    convN_k<256, 512, 6, 10, 3, 5><<<(int)(H4 / 256), 256, 0, stream>>>(h3, wt4, h4);
    {
        int R = 512 * 3 * 5, rpb = (R + NB - 1) / NB;
        reduce1_k<512><<<NB, 256, 0, stream>>>(h4, part, R, rpb);
        stats_k<512><<<1, 512, 0, stream>>>(part, g4, b4, st4, NB, 1.f / R);
        scale_k<512><<<1024, 256, 0, stream>>>(h4, st4, H4 / 4);
    }
    // ---- head ----
    head_k<<<512, 256, 0, stream>>>(h4, W5, y, out);
}

// Round 2
// 2372.126 us; speedup vs baseline: 9.6627x; 9.6627x over previous
//
#include <hip/hip_runtime.h>
#include <hip/hip_bf16.h>
#include <math.h>

#define EPS 1e-5f
#define SLOPE 0.2f

// ---------------------------------------------------------------------------
//  L1: [512,  1,48,80] -> [512, 64,24,40]
//  L2: [512, 64,24,40] -> [512,128,12,20]
//  L3: [512,128,12,20] -> [512,256, 6,10]
//  L4: [512,256, 6,10] -> [512,512, 3, 5]
// NHWC intermediates. Conv2-4 = implicit GEMM: M=B*OH*OW, N=COUT, K=CIN*16.
// Tiles BM=128 x BN=64 x BK=16, 256 threads, 8x4 register tile per thread.
// ---------------------------------------------------------------------------

// ---- weight transpose: OIHW -> [k][co], k = (kh*4+kw)*CIN + ci ----
__global__ __launch_bounds__(256) void twk(const float* __restrict__ W,
                                           float* __restrict__ wT, int O, int I) {
    int idx = blockIdx.x * 256 + threadIdx.x;
    int total = O * I * 16;
    if (idx >= total) return;
    int co = idx % O;
    int rest = idx / O;
    int ci = rest % I;
    int kp = rest / I;
    wT[idx] = W[((size_t)co * I + ci) * 16 + kp];
}

// ---- conv1: C_in=1, 4 outputs (co) per thread, float4 writes ----
__global__ __launch_bounds__(256) void conv1_k(const float* __restrict__ x,
                                               const float* __restrict__ W1,
                                               float* __restrict__ out) {
    int idx = blockIdx.x * 256 + threadIdx.x;   // total = 512*24*40*16
    int cog = idx & 15;
    int rest = idx >> 4;
    int ow = rest % 40; rest /= 40;
    int oh = rest % 24;
    int n  = rest / 24;

    float p[16];
#pragma unroll
    for (int kh = 0; kh < 4; ++kh) {
        int ih = oh * 2 - 1 + kh;
        const float* xr = x + ((size_t)n * 48 + ih) * 80;
#pragma unroll
        for (int kw = 0; kw < 4; ++kw) {
            int iw = ow * 2 - 1 + kw;
            bool ok = ((unsigned)ih < 48u) && ((unsigned)iw < 80u);
            p[kh * 4 + kw] = ok ? xr[iw] : 0.f;
        }
    }
    float acc[4] = {0.f, 0.f, 0.f, 0.f};
#pragma unroll
    for (int j = 0; j < 4; ++j) {
        const float4* wr = (const float4*)(W1 + (cog * 4 + j) * 16);
        float4 wa = wr[0], wb = wr[1], wc = wr[2], wd = wr[3];
        float wk[16] = {wa.x, wa.y, wa.z, wa.w, wb.x, wb.y, wb.z, wb.w,
                        wc.x, wc.y, wc.z, wc.w, wd.x, wd.y, wd.z, wd.w};
#pragma unroll
        for (int k = 0; k < 16; ++k) acc[j] = fmaf(p[k], wk[k], acc[j]);
    }
    float4 v = {acc[0], acc[1], acc[2], acc[3]};
    *(float4*)(out + (((size_t)n * 24 + oh) * 40 + ow) * 64 + cog * 4) = v;
}

// ---- conv2-4: implicit-GEMM, BM=128 BN=64 BK=16, 256 thr, 8x4/thread ----
template<int CIN, int COUT, int IH, int IW, int OH, int OW>
__global__ __launch_bounds__(256) void convG_k(const float* __restrict__ in,
                                               const float* __restrict__ wT,  // [K][COUT]
                                               float* __restrict__ out) {
    constexpr int BM = 128, BN = 64, BK = 16;
    constexpr int K = CIN * 16;
    __shared__ float As[BK][BM];
    __shared__ float Bs[BK][BN];

    const int t = threadIdx.x;
    constexpr int nTilesN = COUT / BN;
    const int bm = blockIdx.x / nTilesN;
    const int bn = blockIdx.x % nTilesN;
    const int m0 = bm * BM;
    const int n0 = bn * BN;

    // --- fixed staging coordinates: 2 A-rows per thread ---
    const int r0  = t >> 2;       // 0..63
    const int seg = t & 3;        // ci sub-offset seg*4
    int rn[2], rih0[2], riw0[2];
#pragma unroll
    for (int i = 0; i < 2; ++i) {
        int gr = m0 + r0 + i * 64;
        int n = gr / (OH * OW);
        int p = gr % (OH * OW);
        int oh = p / OW, ow = p % OW;
        rn[i] = n; rih0[i] = oh * 2 - 1; riw0[i] = ow * 2 - 1;
    }

    // --- compute-thread mapping: 8 rows x 4 cols ---
    const int tr = t >> 4;   // 0..15 -> rows tr*8 .. tr*8+7
    const int tc = t & 15;   // 0..15 -> cols tc*4 .. tc*4+3

    float acc[8][4];
#pragma unroll
    for (int m = 0; m < 8; ++m)
#pragma unroll
        for (int nn = 0; nn < 4; ++nn) acc[m][nn] = 0.f;

    const int kbB = t >> 4;          // B staging row (0..15)
    const int csB = (t & 15) * 4;    // B staging col

    for (int kt = 0; kt < K / BK; ++kt) {
        const int kp  = (kt * BK) / CIN;    // kh*4+kw (BK divides CIN)
        const int ci0 = (kt * BK) % CIN;
        const int kh = kp >> 2, kw = kp & 3;

        // stage A: [BK][BM], k-major (4 scalar writes per float4, 4-way ok)
#pragma unroll
        for (int i = 0; i < 2; ++i) {
            int ih = rih0[i] + kh, iw = riw0[i] + kw;
            float4 v = {0.f, 0.f, 0.f, 0.f};
            if ((unsigned)ih < (unsigned)IH && (unsigned)iw < (unsigned)IW)
                v = *(const float4*)(in + (((size_t)rn[i] * IH + ih) * IW + iw) * CIN
                                      + ci0 + seg * 4);
            int row = r0 + i * 64;
            As[seg * 4 + 0][row] = v.x;
            As[seg * 4 + 1][row] = v.y;
            As[seg * 4 + 2][row] = v.z;
            As[seg * 4 + 3][row] = v.w;
        }
        // stage B: row kbB, cols csB..csB+3 (coalesced)
        {
            float4 b = *(const float4*)(wT + ((size_t)kt * BK + kbB) * COUT + n0 + csB);
            *(float4*)&Bs[kbB][csB] = b;
        }
        __syncthreads();

#pragma unroll
        for (int k = 0; k < BK; ++k) {
            float4 a0 = *(const float4*)&As[k][tr * 8];
            float4 a1 = *(const float4*)&As[k][tr * 8 + 4];
            float4 b  = *(const float4*)&Bs[k][tc * 4];
            float av[8] = {a0.x, a0.y, a0.z, a0.w, a1.x, a1.y, a1.z, a1.w};
            float bv[4] = {b.x, b.y, b.z, b.w};
#pragma unroll
            for (int m = 0; m < 8; ++m)
#pragma unroll
                for (int nn = 0; nn < 4; ++nn)
                    acc[m][nn] = fmaf(av[m], bv[nn], acc[m][nn]);
        }
        __syncthreads();
    }

    // write NHWC: row gr = m0 + tr*8 + m, col n0 + tc*4 (float4, coalesced)
#pragma unroll
    for (int m = 0; m < 8; ++m) {
        int gr = m0 + tr * 8 + m;
        float4 v = {acc[m][0], acc[m][1], acc[m][2], acc[m][3]};
        *(float4*)(out + (size_t)gr * COUT + n0 + tc * 4) = v;
    }
}

// ---- BN stats stage 1: per-block partial sum/sumsq per channel ----
template<int C>
__global__ __launch_bounds__(256) void reduce1_k(const float* __restrict__ h,
                                                 float* __restrict__ part,
                                                 int R, int rpb) {
    int t = threadIdx.x;
    int bid = blockIdx.x;
    int r_lo = bid * rpb;
    int r_hi = min(R, r_lo + rpb);
    if constexpr (C <= 256) {
        constexpr int STEP = 256 / C;
        int c = t & (C - 1);
        float s = 0.f, q = 0.f;
        for (int r = r_lo + (t / C); r < r_hi; r += STEP) {
            float v = h[(size_t)r * C + c];
            s += v; q += v * v;
        }
        __shared__ float ls[256], lq[256];
        ls[t] = s; lq[t] = q; __syncthreads();
        for (int d = 128; d >= C; d >>= 1) {
            if (t < d) { ls[t] += ls[t + d]; lq[t] += lq[t + d]; }
            __syncthreads();
        }
        if (t < C) {
            part[(size_t)bid * 2 * C + t]     = ls[t];
            part[(size_t)bid * 2 * C + C + t] = lq[t];
        }
    } else {  // C == 512
        float s0 = 0.f, q0 = 0.f, s1 = 0.f, q1 = 0.f;
        for (int r = r_lo; r < r_hi; ++r) {
            float v0 = h[(size_t)r * C + t];
            float v1 = h[(size_t)r * C + t + 256];
            s0 += v0; q0 += v0 * v0;
            s1 += v1; q1 += v1 * v1;
        }
        part[(size_t)bid * 2 * C + t]           = s0;
        part[(size_t)bid * 2 * C + t + 256]     = s1;
        part[(size_t)bid * 2 * C + C + t]       = q0;
        part[(size_t)bid * 2 * C + C + t + 256] = q1;
    }
}

// ---- BN stats stage 2 ----
template<int C>
__global__ void stats_k(const float* __restrict__ part,
                        const float* __restrict__ gamma,
                        const float* __restrict__ beta,
                        float* __restrict__ st, int nblocks, float invR) {
    int c = threadIdx.x;
    float s = 0.f, q = 0.f;
    for (int b = 0; b < nblocks; ++b) {
        s += part[(size_t)b * 2 * C + c];
        q += part[(size_t)b * 2 * C + C + c];
    }
    float mean = s * invR;
    float var  = q * invR - mean * mean;
    float sc = gamma[c] * rsqrtf(var + EPS);
    st[c]     = sc;
    st[C + c] = beta[c] - mean * sc;
}

// ---- in-place normalize + LeakyReLU ----
template<int C>
__global__ __launch_bounds__(256) void scale_k(float* __restrict__ h,
                                               const float* __restrict__ st,
                                               size_t n4) {
    size_t i = (size_t)blockIdx.x * 256 + threadIdx.x;
    size_t stride = (size_t)gridDim.x * 256;
    float4* h4 = (float4*)h;
    for (; i < n4; i += stride) {
        float4 v = h4[i];
        int c0 = (int)((i * 4) & (size_t)(C - 1));
        float s0 = st[c0],     s1 = st[c0 + 1],     s2 = st[c0 + 2],     s3 = st[c0 + 3];
        float t0 = st[C + c0], t1 = st[C + c0 + 1], t2 = st[C + c0 + 2], t3 = st[C + c0 + 3];
        v.x = fmaf(v.x, s0, t0); v.x = v.x >= 0.f ? v.x : SLOPE * v.x;
        v.y = fmaf(v.y, s1, t1); v.y = v.y >= 0.f ? v.y : SLOPE * v.y;
        v.z = fmaf(v.z, s2, t2); v.z = v.z >= 0.f ? v.z : SLOPE * v.z;
        v.w = fmaf(v.w, s3, t3); v.w = v.w >= 0.f ? v.w : SLOPE * v.w;
        h4[i] = v;
    }
}

// ---- expert head ----
__global__ __launch_bounds__(256) void head_k(const float* __restrict__ h4,
                                              const float* __restrict__ W5,
                                              const int* __restrict__ y,
                                              float* __restrict__ out) {
    int b = blockIdx.x;
    int t = threadIdx.x;
    int e = y[b];
    const float* w  = W5 + (size_t)e * 7680;
    const float* hb = h4 + (size_t)b * 7680;
    float s = 0.f;
    for (int f = t; f < 7680; f += 256) {
        int c  = f & 511;
        int hw = f >> 9;
        s = fmaf(hb[f], w[c * 15 + hw], s);
    }
    __shared__ float ls[256];
    ls[t] = s; __syncthreads();
    for (int d = 128; d > 0; d >>= 1) {
        if (t < d) ls[t] += ls[t + d];
        __syncthreads();
    }
    if (t == 0) out[b] = ls[0];
}

extern "C" void kernel_launch(void* const* d_in, const int* in_sizes, int n_in,
                              void* d_out, int out_size, void* d_ws, size_t ws_size,
                              hipStream_t stream) {
    const float* x  = (const float*)d_in[0];
    const float* W1 = (const float*)d_in[1];
    const float* g1 = (const float*)d_in[2];
    const float* b1 = (const float*)d_in[3];
    const float* W2 = (const float*)d_in[4];
    const float* g2 = (const float*)d_in[5];
    const float* b2 = (const float*)d_in[6];
    const float* W3 = (const float*)d_in[7];
    const float* g3 = (const float*)d_in[8];
    const float* b3 = (const float*)d_in[9];
    const float* W4 = (const float*)d_in[10];
    const float* g4 = (const float*)d_in[11];
    const float* b4 = (const float*)d_in[12];
    const float* W5 = (const float*)d_in[13];
    const int*   y  = (const int*)d_in[14];
    float* out = (float*)d_out;

    const size_t H1 = (size_t)512 * 24 * 40 * 64;
    const size_t H2 = (size_t)512 * 12 * 20 * 128;
    const size_t H3 = (size_t)512 * 6  * 10 * 256;
    const size_t H4 = (size_t)512 * 3  * 5  * 512;
    float* ws  = (float*)d_ws;
    float* h1  = ws;
    float* h2  = h1 + H1;
    float* h3  = h1;                  // reuse
    float* h4  = h2;                  // reuse
    float* wt2 = h2 + H2;             // 1024*128   = 131072
    float* wt3 = wt2 + 131072;        // 2048*256   = 524288
    float* wt4 = wt3 + 524288;        // 4096*512   = 2097152
    float* part = wt4 + 2097152;
    float* st1 = part + 524288;
    float* st2 = st1 + 128;
    float* st3 = st2 + 256;
    float* st4 = st3 + 512;

    const int NB = 512;

    twk<<<(128 * 64 * 16 + 255) / 256, 256, 0, stream>>>(W2, wt2, 128, 64);
    twk<<<(256 * 128 * 16 + 255) / 256, 256, 0, stream>>>(W3, wt3, 256, 128);
    twk<<<(512 * 256 * 16 + 255) / 256, 256, 0, stream>>>(W4, wt4, 512, 256);

    // ---- L1 ----
    conv1_k<<<(int)(512 * 24 * 40 * 16 / 256), 256, 0, stream>>>(x, W1, h1);
    {
        int R = 512 * 24 * 40, rpb = (R + NB - 1) / NB;
        reduce1_k<64><<<NB, 256, 0, stream>>>(h1, part, R, rpb);
        stats_k<64><<<1, 64, 0, stream>>>(part, g1, b1, st1, NB, 1.f / R);
        scale_k<64><<<4096, 256, 0, stream>>>(h1, st1, H1 / 4);
    }
    // ---- L2 ----  M=122880 -> 960 m-tiles, 2 n-tiles
    convG_k<64, 128, 24, 40, 12, 20><<<960 * 2, 256, 0, stream>>>(h1, wt2, h2);
    {
        int R = 512 * 12 * 20, rpb = (R + NB - 1) / NB;
        reduce1_k<128><<<NB, 256, 0, stream>>>(h2, part, R, rpb);
        stats_k<128><<<1, 128, 0, stream>>>(part, g2, b2, st2, NB, 1.f / R);
        scale_k<128><<<4096, 256, 0, stream>>>(h2, st2, H2 / 4);
    }
    // ---- L3 ----  M=30720 -> 240 m-tiles, 4 n-tiles
    convG_k<128, 256, 12, 20, 6, 10><<<240 * 4, 256, 0, stream>>>(h2, wt3, h3);
    {
        int R = 512 * 6 * 10, rpb = (R + NB - 1) / NB;
        reduce1_k<256><<<NB, 256, 0, stream>>>(h3, part, R, rpb);
        stats_k<256><<<1, 256, 0, stream>>>(part, g3, b3, st3, NB, 1.f / R);
        scale_k<256><<<2048, 256, 0, stream>>>(h3, st3, H3 / 4);
    }
    // ---- L4 ----  M=7680 -> 60 m-tiles, 8 n-tiles
    convG_k<256, 512, 6, 10, 3, 5><<<60 * 8, 256, 0, stream>>>(h3, wt4, h4);
    {
        int R = 512 * 3 * 5, rpb = (R + NB - 1) / NB;
        reduce1_k<512><<<NB, 256, 0, stream>>>(h4, part, R, rpb);
        stats_k<512><<<1, 512, 0, stream>>>(part, g4, b4, st4, NB, 1.f / R);
        scale_k<512><<<1024, 256, 0, stream>>>(h4, st4, H4 / 4);
    }
    // ---- head ----
    head_k<<<512, 256, 0, stream>>>(h4, W5, y, out);
}

// Round 3
// 1096.952 us; speedup vs baseline: 20.8954x; 2.1625x over previous
//
#include <hip/hip_runtime.h>
#include <hip/hip_bf16.h>
#include <math.h>

#define EPS 1e-5f
#define SLOPE 0.2f

// ---------------------------------------------------------------------------
//  L1: [512,  1,48,80] -> [512, 64,24,40]
//  L2: [512, 64,24,40] -> [512,128,12,20]
//  L3: [512,128,12,20] -> [512,256, 6,10]
//  L4: [512,256, 6,10] -> [512,512, 3, 5]
// All activations bf16 NHWC. Conv2-4 = MFMA implicit GEMM
// (mfma_f32_16x16x32_bf16): BM=BN=128, BK=32, 4 waves, 64x64 per wave.
// LDS tiles padded to 40 bf16/row (80B) -> conflict-free ds_read_b128.
// BN training stats via deterministic two-stage reduction on bf16 h.
// ---------------------------------------------------------------------------

typedef short bf16x8 __attribute__((ext_vector_type(8)));
typedef short short4v __attribute__((ext_vector_type(4)));
typedef float f32x4 __attribute__((ext_vector_type(4)));

__device__ __forceinline__ float bf2f(short s) {
    unsigned int u = ((unsigned int)(unsigned short)s) << 16;
    float f;
    __builtin_memcpy(&f, &u, 4);
    return f;
}
__device__ __forceinline__ short f2bf(float f) {
    unsigned int u;
    __builtin_memcpy(&u, &f, 4);
    u = (u + 0x7FFFu + ((u >> 16) & 1u)) >> 16;   // RNE
    return (short)(unsigned short)u;
}

// ---- weight cast+reorder: OIHW fp32 -> bf16 [co][kp*CIN + ci] ----
__global__ __launch_bounds__(256) void twkB_k(const float* __restrict__ W,
                                              short* __restrict__ wB, int O, int I) {
    int idx = blockIdx.x * 256 + threadIdx.x;
    int total = O * I * 16;
    if (idx >= total) return;
    int K = I * 16;
    int co = idx / K;
    int rem = idx % K;
    int kp = rem / I;
    int ci = rem % I;
    wB[idx] = f2bf(W[((size_t)co * I + ci) * 16 + kp]);
}

// ---- conv1: C_in=1 fp32 compute, bf16 NHWC out ----
__global__ __launch_bounds__(256) void conv1_k(const float* __restrict__ x,
                                               const float* __restrict__ W1,
                                               short* __restrict__ out) {
    int idx = blockIdx.x * 256 + threadIdx.x;   // 512*24*40*16
    int cog = idx & 15;
    int rest = idx >> 4;
    int ow = rest % 40; rest /= 40;
    int oh = rest % 24;
    int n  = rest / 24;

    float p[16];
#pragma unroll
    for (int kh = 0; kh < 4; ++kh) {
        int ih = oh * 2 - 1 + kh;
        const float* xr = x + ((size_t)n * 48 + ih) * 80;
#pragma unroll
        for (int kw = 0; kw < 4; ++kw) {
            int iw = ow * 2 - 1 + kw;
            bool ok = ((unsigned)ih < 48u) && ((unsigned)iw < 80u);
            p[kh * 4 + kw] = ok ? xr[iw] : 0.f;
        }
    }
    short4v v;
#pragma unroll
    for (int j = 0; j < 4; ++j) {
        const float4* wr = (const float4*)(W1 + (cog * 4 + j) * 16);
        float4 wa = wr[0], wb = wr[1], wc = wr[2], wd = wr[3];
        float wk[16] = {wa.x, wa.y, wa.z, wa.w, wb.x, wb.y, wb.z, wb.w,
                        wc.x, wc.y, wc.z, wc.w, wd.x, wd.y, wd.z, wd.w};
        float acc = 0.f;
#pragma unroll
        for (int k = 0; k < 16; ++k) acc = fmaf(p[k], wk[k], acc);
        v[j] = f2bf(acc);
    }
    *(short4v*)(out + (((size_t)n * 24 + oh) * 40 + ow) * 64 + cog * 4) = v;
}

// ---- conv2-4: MFMA implicit GEMM, bf16 in/out ----
template<int CIN, int COUT, int IH, int IW, int OH, int OW>
__global__ __launch_bounds__(256) void convM_k(const short* __restrict__ in,
                                               const short* __restrict__ wB,   // [COUT][K]
                                               short* __restrict__ out) {
    constexpr int K  = CIN * 16;
    constexpr int BM = 128, BN = 128, BK = 32;
    constexpr int LDP = 40;                       // padded row (bf16), 80 B
    __shared__ short As[BM * LDP];
    __shared__ short Bs[BN * LDP];

    const int t = threadIdx.x;
    constexpr int nTN = COUT / BN;
    const int bm = (int)blockIdx.x / nTN, bn = (int)blockIdx.x % nTN;
    const int m0 = bm * BM, n0 = bn * BN;

    // staging: thread t -> rows (t>>2, t>>2+64), 16B chunk (t&3)
    const int sr = t >> 2, sc = t & 3;
    int pn[2], ph[2], pw[2];
#pragma unroll
    for (int i = 0; i < 2; ++i) {
        int gr = m0 + sr + i * 64;
        int n = gr / (OH * OW), p = gr % (OH * OW);
        pn[i] = n; ph[i] = (p / OW) * 2 - 1; pw[i] = (p % OW) * 2 - 1;
    }
    // fragment mapping: 4 waves in 2x2, each 64x64
    const int w = t >> 6, l = t & 63;
    const int wr = (w >> 1) * 64, wc = (w & 1) * 64;
    const int fr = l & 15, kq = l >> 4;

    f32x4 acc[4][4];
#pragma unroll
    for (int mi = 0; mi < 4; ++mi)
#pragma unroll
        for (int ni = 0; ni < 4; ++ni) acc[mi][ni] = 0;

    for (int kt = 0; kt < K / BK; ++kt) {
        const int kp = (kt * BK) / CIN, ci0 = (kt * BK) % CIN;
        const int kh = kp >> 2, kw = kp & 3;
        // stage A (predicated boundary)
#pragma unroll
        for (int i = 0; i < 2; ++i) {
            int ih = ph[i] + kh, iw = pw[i] + kw;
            bf16x8 v = 0;
            if ((unsigned)ih < (unsigned)IH && (unsigned)iw < (unsigned)IW)
                v = *(const bf16x8*)(in + (((size_t)pn[i] * IH + ih) * IW + iw) * CIN
                                        + ci0 + sc * 8);
            *(bf16x8*)(As + (sr + i * 64) * LDP + sc * 8) = v;
        }
        // stage B (contiguous rows of wB)
#pragma unroll
        for (int i = 0; i < 2; ++i) {
            bf16x8 v = *(const bf16x8*)(wB + (size_t)(n0 + sr + i * 64) * K
                                           + kt * BK + sc * 8);
            *(bf16x8*)(Bs + (sr + i * 64) * LDP + sc * 8) = v;
        }
        __syncthreads();

        bf16x8 af[4], bf[4];
#pragma unroll
        for (int mi = 0; mi < 4; ++mi)
            af[mi] = *(const bf16x8*)(As + (wr + mi * 16 + fr) * LDP + kq * 8);
#pragma unroll
        for (int ni = 0; ni < 4; ++ni)
            bf[ni] = *(const bf16x8*)(Bs + (wc + ni * 16 + fr) * LDP + kq * 8);
#pragma unroll
        for (int mi = 0; mi < 4; ++mi)
#pragma unroll
            for (int ni = 0; ni < 4; ++ni)
                acc[mi][ni] = __builtin_amdgcn_mfma_f32_16x16x32_bf16(
                    af[mi], bf[ni], acc[mi][ni], 0, 0, 0);
        __syncthreads();
    }

    // epilogue: D row = (lane>>4)*4 + reg, col = lane&15  [m89-verified layout]
#pragma unroll
    for (int mi = 0; mi < 4; ++mi)
#pragma unroll
        for (int ni = 0; ni < 4; ++ni)
#pragma unroll
            for (int r = 0; r < 4; ++r) {
                int row = m0 + wr + mi * 16 + kq * 4 + r;
                int col = n0 + wc + ni * 16 + fr;
                out[(size_t)row * COUT + col] = f2bf(acc[mi][ni][r]);
            }
}

// ---- BN stats stage 1 (bf16 input, short4 vec loads) ----
template<int C>
__global__ __launch_bounds__(256) void reduceB_k(const short* __restrict__ h,
                                                 float* __restrict__ part,
                                                 int R, int rpb) {
    constexpr int CG = C / 4;          // threads covering one row
    constexpr int STEP = 256 / CG;
    int t = threadIdx.x;
    int c4 = t % CG, rsub = t / CG;
    int r_lo = blockIdx.x * rpb, r_hi = min(R, r_lo + rpb);
    float s[4] = {0, 0, 0, 0}, q[4] = {0, 0, 0, 0};
    for (int r = r_lo + rsub; r < r_hi; r += STEP) {
        short4v v = *(const short4v*)(h + (size_t)r * C + c4 * 4);
#pragma unroll
        for (int j = 0; j < 4; ++j) { float f = bf2f(v[j]); s[j] += f; q[j] += f * f; }
    }
    __shared__ float ls[4][256], lq[4][256];
#pragma unroll
    for (int j = 0; j < 4; ++j) { ls[j][t] = s[j]; lq[j][t] = q[j]; }
    __syncthreads();
    for (int d = 128; d >= CG; d >>= 1) {
        if (t < d) {
#pragma unroll
            for (int j = 0; j < 4; ++j) { ls[j][t] += ls[j][t + d]; lq[j][t] += lq[j][t + d]; }
        }
        __syncthreads();
    }
    if (t < CG) {
#pragma unroll
        for (int j = 0; j < 4; ++j) {
            part[(size_t)blockIdx.x * 2 * C + c4 * 4 + j]     = ls[j][t];
            part[(size_t)blockIdx.x * 2 * C + C + c4 * 4 + j] = lq[j][t];
        }
    }
}

// ---- BN stats stage 2 ----
template<int C>
__global__ void stats_k(const float* __restrict__ part,
                        const float* __restrict__ gamma,
                        const float* __restrict__ beta,
                        float* __restrict__ st, int nblocks, float invR) {
    int c = threadIdx.x;
    float s = 0.f, q = 0.f;
    for (int b = 0; b < nblocks; ++b) {
        s += part[(size_t)b * 2 * C + c];
        q += part[(size_t)b * 2 * C + C + c];
    }
    float mean = s * invR;
    float var  = q * invR - mean * mean;
    float sc = gamma[c] * rsqrtf(var + EPS);
    st[c]     = sc;
    st[C + c] = beta[c] - mean * sc;
}

// ---- in-place bf16 normalize + LeakyReLU (16B vectors) ----
template<int C>
__global__ __launch_bounds__(256) void scaleB_k(short* __restrict__ h,
                                                const float* __restrict__ st,
                                                size_t n8) {
    __shared__ float sst[1024];
    int t = threadIdx.x;
    for (int j = t; j < 2 * C; j += 256) sst[j] = st[j];
    __syncthreads();
    size_t i = (size_t)blockIdx.x * 256 + t;
    size_t stride = (size_t)gridDim.x * 256;
    bf16x8* h8 = (bf16x8*)h;
    for (; i < n8; i += stride) {
        bf16x8 v = h8[i];
        int c0 = (int)((i * 8) & (size_t)(C - 1));
#pragma unroll
        for (int j = 0; j < 8; ++j) {
            float f = bf2f(v[j]);
            f = fmaf(f, sst[c0 + j], sst[C + c0 + j]);
            f = f >= 0.f ? f : SLOPE * f;
            v[j] = f2bf(f);
        }
        h8[i] = v;
    }
}

// ---- expert head: bf16 h4, fp32 W5 ----
__global__ __launch_bounds__(256) void head_k(const short* __restrict__ h4,
                                              const float* __restrict__ W5,
                                              const int* __restrict__ y,
                                              float* __restrict__ out) {
    int b = blockIdx.x;
    int t = threadIdx.x;
    int e = y[b];
    const float* wp = W5 + (size_t)e * 7680;   // [512][3][5]: c*15 + hw
    const short* hb = h4 + (size_t)b * 7680;   // NHWC: hw*512 + c
    float s = 0.f;
    for (int f = t; f < 7680; f += 256) {
        int c  = f & 511;
        int hw = f >> 9;
        s = fmaf(bf2f(hb[f]), wp[c * 15 + hw], s);
    }
    __shared__ float ls[256];
    ls[t] = s; __syncthreads();
    for (int d = 128; d > 0; d >>= 1) {
        if (t < d) ls[t] += ls[t + d];
        __syncthreads();
    }
    if (t == 0) out[b] = ls[0];
}

extern "C" void kernel_launch(void* const* d_in, const int* in_sizes, int n_in,
                              void* d_out, int out_size, void* d_ws, size_t ws_size,
                              hipStream_t stream) {
    const float* x  = (const float*)d_in[0];
    const float* W1 = (const float*)d_in[1];
    const float* g1 = (const float*)d_in[2];
    const float* b1 = (const float*)d_in[3];
    const float* W2 = (const float*)d_in[4];
    const float* g2 = (const float*)d_in[5];
    const float* b2 = (const float*)d_in[6];
    const float* W3 = (const float*)d_in[7];
    const float* g3 = (const float*)d_in[8];
    const float* b3 = (const float*)d_in[9];
    const float* W4 = (const float*)d_in[10];
    const float* g4 = (const float*)d_in[11];
    const float* b4 = (const float*)d_in[12];
    const float* W5 = (const float*)d_in[13];
    const int*   y  = (const int*)d_in[14];
    float* out = (float*)d_out;

    // element counts (bf16)
    const size_t H1 = (size_t)512 * 24 * 40 * 64;    // 31,457,280
    const size_t H2 = (size_t)512 * 12 * 20 * 128;   // 15,728,640
    const size_t H3 = (size_t)512 * 6  * 10 * 256;   //  7,864,320
    const size_t H4 = (size_t)512 * 3  * 5  * 512;   //  3,932,160

    float* ws = (float*)d_ws;   // carve in float units; total ~126 MB
    short* h1b = (short*)ws;                          // H1 shorts
    short* h2b = (short*)(ws + H1 / 2);
    short* h3b = (short*)(ws + H1 / 2 + H2 / 2);
    short* h4b = (short*)(ws + H1 / 2 + H2 / 2 + H3 / 2);
    float* fbase = ws + H1 / 2 + H2 / 2 + H3 / 2 + H4 / 2;
    short* wB2 = (short*)fbase;                       // 131072 sh = 65536 f
    short* wB3 = (short*)(fbase + 65536);             // 524288 sh = 262144 f
    short* wB4 = (short*)(fbase + 65536 + 262144);    // 2097152 sh = 1048576 f
    float* part = fbase + 65536 + 262144 + 1048576;   // 524288 f
    float* st1 = part + 524288;
    float* st2 = st1 + 128;
    float* st3 = st2 + 256;
    float* st4 = st3 + 512;

    const int NB = 512;

    twkB_k<<<(128 * 64 * 16 + 255) / 256, 256, 0, stream>>>(W2, wB2, 128, 64);
    twkB_k<<<(256 * 128 * 16 + 255) / 256, 256, 0, stream>>>(W3, wB3, 256, 128);
    twkB_k<<<(512 * 256 * 16 + 255) / 256, 256, 0, stream>>>(W4, wB4, 512, 256);

    // ---- L1 ----
    conv1_k<<<512 * 24 * 40 * 16 / 256, 256, 0, stream>>>(x, W1, h1b);
    {
        int R = 512 * 24 * 40, rpb = (R + NB - 1) / NB;
        reduceB_k<64><<<NB, 256, 0, stream>>>(h1b, part, R, rpb);
        stats_k<64><<<1, 64, 0, stream>>>(part, g1, b1, st1, NB, 1.f / R);
        scaleB_k<64><<<2048, 256, 0, stream>>>(h1b, st1, H1 / 8);
    }
    // ---- L2 ----  M=122880 -> 960 tiles
    convM_k<64, 128, 24, 40, 12, 20><<<960, 256, 0, stream>>>(h1b, wB2, h2b);
    {
        int R = 512 * 12 * 20, rpb = (R + NB - 1) / NB;
        reduceB_k<128><<<NB, 256, 0, stream>>>(h2b, part, R, rpb);
        stats_k<128><<<1, 128, 0, stream>>>(part, g2, b2, st2, NB, 1.f / R);
        scaleB_k<128><<<2048, 256, 0, stream>>>(h2b, st2, H2 / 8);
    }
    // ---- L3 ----  M=30720 -> 240 m-tiles x 2 n-tiles
    convM_k<128, 256, 12, 20, 6, 10><<<240 * 2, 256, 0, stream>>>(h2b, wB3, h3b);
    {
        int R = 512 * 6 * 10, rpb = (R + NB - 1) / NB;
        reduceB_k<256><<<NB, 256, 0, stream>>>(h3b, part, R, rpb);
        stats_k<256><<<1, 256, 0, stream>>>(part, g3, b3, st3, NB, 1.f / R);
        scaleB_k<256><<<2048, 256, 0, stream>>>(h3b, st3, H3 / 8);
    }
    // ---- L4 ----  M=7680 -> 60 m-tiles x 4 n-tiles
    convM_k<256, 512, 6, 10, 3, 5><<<60 * 4, 256, 0, stream>>>(h3b, wB4, h4b);
    {
        int R = 512 * 3 * 5, rpb = (R + NB - 1) / NB;
        reduceB_k<512><<<NB, 256, 0, stream>>>(h4b, part, R, rpb);
        stats_k<512><<<1, 512, 0, stream>>>(part, g4, b4, st4, NB, 1.f / R);
        scaleB_k<512><<<1024, 256, 0, stream>>>(h4b, st4, H4 / 8);
    }
    // ---- head ----
    head_k<<<512, 256, 0, stream>>>(h4b, W5, y, out);
}

// Round 4
// 820.467 us; speedup vs baseline: 27.9368x; 1.3370x over previous
//
#include <hip/hip_runtime.h>
#include <hip/hip_bf16.h>
#include <math.h>

#define EPS 1e-5f
#define SLOPE 0.2f

// ---------------------------------------------------------------------------
//  L1: [512,  1,48,80] -> [512, 64,24,40]
//  L2: [512, 64,24,40] -> [512,128,12,20]
//  L3: [512,128,12,20] -> [512,256, 6,10]
//  L4: [512,256, 6,10] -> [512,512, 3, 5]
// bf16 NHWC activations. Conv2-4 = MFMA implicit GEMM (16x16x32 bf16),
// BM=128, BK=32, BN templated (128/128/64), 4 waves. BN stage-1 reduction
// fused into convM epilogue from f32 accumulators. conv1 = pixel-per-lane,
// all 64 cout per thread, W1 broadcast from LDS.
// ---------------------------------------------------------------------------

typedef short bf16x8 __attribute__((ext_vector_type(8)));
typedef short short4v __attribute__((ext_vector_type(4)));
typedef float f32x4 __attribute__((ext_vector_type(4)));

__device__ __forceinline__ float bf2f(short s) {
    unsigned int u = ((unsigned int)(unsigned short)s) << 16;
    float f;
    __builtin_memcpy(&f, &u, 4);
    return f;
}
__device__ __forceinline__ short f2bf(float f) {
    unsigned int u;
    __builtin_memcpy(&u, &f, 4);
    u = (u + 0x7FFFu + ((u >> 16) & 1u)) >> 16;   // RNE
    return (short)(unsigned short)u;
}

// ---- weight cast+reorder: OIHW fp32 -> bf16 [co][kp*CIN + ci] ----
__global__ __launch_bounds__(256) void twkB_k(const float* __restrict__ W,
                                              short* __restrict__ wB, int O, int I) {
    int idx = blockIdx.x * 256 + threadIdx.x;
    int total = O * I * 16;
    if (idx >= total) return;
    int K = I * 16;
    int co = idx / K;
    int rem = idx % K;
    int kp = rem / I;
    int ci = rem % I;
    wB[idx] = f2bf(W[((size_t)co * I + ci) * 16 + kp]);
}

// ---- conv1: pixel-per-lane, all 64 cout per thread, W1 in LDS ----
__global__ __launch_bounds__(256) void conv1_k(const float* __restrict__ x,
                                               const float* __restrict__ W1,
                                               short* __restrict__ out) {
    __shared__ float wlds[1024];          // W1 [64 co][16 k] fp32
    int t = threadIdx.x;
    ((float4*)wlds)[t] = ((const float4*)W1)[t];
    __syncthreads();

    int pixel = blockIdx.x * 256 + t;     // 512*24*40 = 491520 pixels
    int n  = pixel / 960;
    int p  = pixel % 960;
    int oh = p / 40, ow = p % 40;
    int ih0 = oh * 2 - 1, iw0 = ow * 2 - 1;

    float patch[16];
#pragma unroll
    for (int kh = 0; kh < 4; ++kh) {
        int ih = ih0 + kh;
#pragma unroll
        for (int kw = 0; kw < 4; ++kw) {
            int iw = iw0 + kw;
            bool ok = ((unsigned)ih < 48u) && ((unsigned)iw < 80u);
            patch[kh * 4 + kw] = ok ? x[((size_t)n * 48 + ih) * 80 + iw] : 0.f;
        }
    }
#pragma unroll
    for (int cog = 0; cog < 8; ++cog) {
        bf16x8 v;
#pragma unroll
        for (int j = 0; j < 8; ++j) {
            const float4* wv = (const float4*)(wlds + (cog * 8 + j) * 16);
            float4 w0 = wv[0], w1 = wv[1], w2 = wv[2], w3 = wv[3];
            float a = 0.f;
            a = fmaf(patch[0],  w0.x, a); a = fmaf(patch[1],  w0.y, a);
            a = fmaf(patch[2],  w0.z, a); a = fmaf(patch[3],  w0.w, a);
            a = fmaf(patch[4],  w1.x, a); a = fmaf(patch[5],  w1.y, a);
            a = fmaf(patch[6],  w1.z, a); a = fmaf(patch[7],  w1.w, a);
            a = fmaf(patch[8],  w2.x, a); a = fmaf(patch[9],  w2.y, a);
            a = fmaf(patch[10], w2.z, a); a = fmaf(patch[11], w2.w, a);
            a = fmaf(patch[12], w3.x, a); a = fmaf(patch[13], w3.y, a);
            a = fmaf(patch[14], w3.z, a); a = fmaf(patch[15], w3.w, a);
            v[j] = f2bf(a);
        }
        *(bf16x8*)(out + (size_t)pixel * 64 + cog * 8) = v;
    }
}

// ---- conv2-4: MFMA implicit GEMM + fused BN-partial epilogue ----
// part[bid] = { sum[BN], sumsq[BN] } over the block's BM rows (f32 accs).
template<int CIN, int COUT, int BN, int IH, int IW, int OH, int OW>
__global__ __launch_bounds__(256) void convM_k(const short* __restrict__ in,
                                               const short* __restrict__ wB,   // [COUT][K]
                                               short* __restrict__ out,
                                               float* __restrict__ part) {
    constexpr int K  = CIN * 16;
    constexpr int BM = 128, BK = 32;
    constexpr int NI = BN / 32;                   // ni repeats per wave
    constexpr int LDP = 40;                       // padded row (bf16), 80 B
    __shared__ short As[BM * LDP];
    __shared__ short Bs[BN * LDP];

    const int t = threadIdx.x;
    constexpr int nTN = COUT / BN;
    const int bm = (int)blockIdx.x / nTN, bn = (int)blockIdx.x % nTN;
    const int m0 = bm * BM, n0 = bn * BN;

    // staging coords: thread t -> rows (t>>2 [,+64]), 16B chunk (t&3)
    const int sr = t >> 2, sc = t & 3;
    int pn[2], ph[2], pw[2];
#pragma unroll
    for (int i = 0; i < 2; ++i) {
        int gr = m0 + sr + i * 64;
        int n = gr / (OH * OW), p = gr % (OH * OW);
        pn[i] = n; ph[i] = (p / OW) * 2 - 1; pw[i] = (p % OW) * 2 - 1;
    }
    // 4 waves in 2x2; wave tile 64 x (BN/2)
    const int w = t >> 6, l = t & 63;
    const int wr = (w >> 1) * 64, wc = (w & 1) * (BN / 2);
    const int fr = l & 15, kq = l >> 4;

    f32x4 acc[4][NI];
#pragma unroll
    for (int mi = 0; mi < 4; ++mi)
#pragma unroll
        for (int ni = 0; ni < NI; ++ni) acc[mi][ni] = 0;

    for (int kt = 0; kt < K / BK; ++kt) {
        const int kp = (kt * BK) / CIN, ci0 = (kt * BK) % CIN;
        const int kh = kp >> 2, kw = kp & 3;
        // stage A (predicated boundary)
#pragma unroll
        for (int i = 0; i < 2; ++i) {
            int ih = ph[i] + kh, iw = pw[i] + kw;
            bf16x8 v = 0;
            if ((unsigned)ih < (unsigned)IH && (unsigned)iw < (unsigned)IW)
                v = *(const bf16x8*)(in + (((size_t)pn[i] * IH + ih) * IW + iw) * CIN
                                        + ci0 + sc * 8);
            *(bf16x8*)(As + (sr + i * 64) * LDP + sc * 8) = v;
        }
        // stage B (contiguous rows of wB), BN/64 rows per thread
#pragma unroll
        for (int i = 0; i < BN / 64; ++i) {
            bf16x8 v = *(const bf16x8*)(wB + (size_t)(n0 + sr + i * 64) * K
                                           + kt * BK + sc * 8);
            *(bf16x8*)(Bs + (sr + i * 64) * LDP + sc * 8) = v;
        }
        __syncthreads();

        bf16x8 af[4], bfr[NI];
#pragma unroll
        for (int mi = 0; mi < 4; ++mi)
            af[mi] = *(const bf16x8*)(As + (wr + mi * 16 + fr) * LDP + kq * 8);
#pragma unroll
        for (int ni = 0; ni < NI; ++ni)
            bfr[ni] = *(const bf16x8*)(Bs + (wc + ni * 16 + fr) * LDP + kq * 8);
#pragma unroll
        for (int mi = 0; mi < 4; ++mi)
#pragma unroll
            for (int ni = 0; ni < NI; ++ni)
                acc[mi][ni] = __builtin_amdgcn_mfma_f32_16x16x32_bf16(
                    af[mi], bfr[ni], acc[mi][ni], 0, 0, 0);
        __syncthreads();
    }

    // store raw conv output (D: row = kq*4+reg, col = fr)
#pragma unroll
    for (int mi = 0; mi < 4; ++mi)
#pragma unroll
        for (int ni = 0; ni < NI; ++ni)
#pragma unroll
            for (int r = 0; r < 4; ++r) {
                int row = m0 + wr + mi * 16 + kq * 4 + r;
                int col = n0 + wc + ni * 16 + fr;
                out[(size_t)row * COUT + col] = f2bf(acc[mi][ni][r]);
            }

    // fused BN stage-1: per-block channel partials from f32 accs
    float* red = (float*)As;               // 8 * BN * 2 f32 <= 8 KB, aliases As
    // (last loop iteration ended with __syncthreads -> As free)
#pragma unroll
    for (int ni = 0; ni < NI; ++ni) {
        float s = 0.f, q = 0.f;
#pragma unroll
        for (int mi = 0; mi < 4; ++mi)
#pragma unroll
            for (int r = 0; r < 4; ++r) {
                float v = acc[mi][ni][r];
                s += v; q = fmaf(v, v, q);
            }
        int slot = (w >> 1) * 4 + kq;      // 0..7
        int ch = wc + ni * 16 + fr;        // 0..BN-1
        red[(slot * BN + ch) * 2 + 0] = s;
        red[(slot * BN + ch) * 2 + 1] = q;
    }
    __syncthreads();
    if (t < BN) {
        float s = 0.f, q = 0.f;
#pragma unroll
        for (int slot = 0; slot < 8; ++slot) {
            s += red[(slot * BN + t) * 2 + 0];
            q += red[(slot * BN + t) * 2 + 1];
        }
        part[(size_t)blockIdx.x * (2 * BN) + t]      = s;
        part[(size_t)blockIdx.x * (2 * BN) + BN + t] = q;
    }
}

// ---- BN stats stage 1 for h1 (bf16 input) ----
template<int C>
__global__ __launch_bounds__(256) void reduceB_k(const short* __restrict__ h,
                                                 float* __restrict__ part,
                                                 int R, int rpb) {
    constexpr int CG = C / 4;
    constexpr int STEP = 256 / CG;
    int t = threadIdx.x;
    int c4 = t % CG, rsub = t / CG;
    int r_lo = blockIdx.x * rpb, r_hi = min(R, r_lo + rpb);
    float s[4] = {0, 0, 0, 0}, q[4] = {0, 0, 0, 0};
    for (int r = r_lo + rsub; r < r_hi; r += STEP) {
        short4v v = *(const short4v*)(h + (size_t)r * C + c4 * 4);
#pragma unroll
        for (int j = 0; j < 4; ++j) { float f = bf2f(v[j]); s[j] += f; q[j] += f * f; }
    }
    __shared__ float ls[4][256], lq[4][256];
#pragma unroll
    for (int j = 0; j < 4; ++j) { ls[j][t] = s[j]; lq[j][t] = q[j]; }
    __syncthreads();
    for (int d = 128; d >= CG; d >>= 1) {
        if (t < d) {
#pragma unroll
            for (int j = 0; j < 4; ++j) { ls[j][t] += ls[j][t + d]; lq[j][t] += lq[j][t + d]; }
        }
        __syncthreads();
    }
    if (t < CG) {
#pragma unroll
        for (int j = 0; j < 4; ++j) {
            part[(size_t)blockIdx.x * 2 * C + c4 * 4 + j]     = ls[j][t];
            part[(size_t)blockIdx.x * 2 * C + C + c4 * 4 + j] = lq[j][t];
        }
    }
}

// ---- stats stage 2 for reduceB layout (stride 2C per block) ----
template<int C>
__global__ void stats_k(const float* __restrict__ part,
                        const float* __restrict__ gamma,
                        const float* __restrict__ beta,
                        float* __restrict__ st, int nblocks, float invR) {
    int c = threadIdx.x;
    float s = 0.f, q = 0.f;
    for (int b = 0; b < nblocks; ++b) {
        s += part[(size_t)b * 2 * C + c];
        q += part[(size_t)b * 2 * C + C + c];
    }
    float mean = s * invR;
    float var  = q * invR - mean * mean;
    float sc = gamma[c] * rsqrtf(var + EPS);
    st[c]     = sc;
    st[C + c] = beta[c] - mean * sc;
}

// ---- stats stage 2 for convM-epilogue layout (BN local ch per block) ----
template<int C, int BN>
__global__ void stats2_k(const float* __restrict__ part,
                         const float* __restrict__ gamma,
                         const float* __restrict__ beta,
                         float* __restrict__ st, int nTM, float invR) {
    constexpr int NTN = C / BN;
    int c = threadIdx.x;          // blockDim == C
    int bn = c / BN, cc = c % BN;
    float s = 0.f, q = 0.f;
    for (int bm = 0; bm < nTM; ++bm) {
        size_t idx = (size_t)(bm * NTN + bn) * (2 * BN);
        s += part[idx + cc];
        q += part[idx + BN + cc];
    }
    float mean = s * invR;
    float var  = q * invR - mean * mean;
    float sc = gamma[c] * rsqrtf(var + EPS);
    st[c]     = sc;
    st[C + c] = beta[c] - mean * sc;
}

// ---- in-place bf16 normalize + LeakyReLU ----
template<int C>
__global__ __launch_bounds__(256) void scaleB_k(short* __restrict__ h,
                                                const float* __restrict__ st,
                                                size_t n8) {
    __shared__ float sst[1024];
    int t = threadIdx.x;
    for (int j = t; j < 2 * C; j += 256) sst[j] = st[j];
    __syncthreads();
    size_t i = (size_t)blockIdx.x * 256 + t;
    size_t stride = (size_t)gridDim.x * 256;
    bf16x8* h8 = (bf16x8*)h;
    for (; i < n8; i += stride) {
        bf16x8 v = h8[i];
        int c0 = (int)((i * 8) & (size_t)(C - 1));
#pragma unroll
        for (int j = 0; j < 8; ++j) {
            float f = bf2f(v[j]);
            f = fmaf(f, sst[c0 + j], sst[C + c0 + j]);
            f = fmaxf(f, SLOPE * f);
            v[j] = f2bf(f);
        }
        h8[i] = v;
    }
}

// ---- expert head with fused st4 normalize+lrelu ----
__global__ __launch_bounds__(256) void head_k(const short* __restrict__ h4,
                                              const float* __restrict__ W5,
                                              const int* __restrict__ y,
                                              const float* __restrict__ st,
                                              float* __restrict__ out) {
    __shared__ float sst[1024];
    int t = threadIdx.x;
#pragma unroll
    for (int j = 0; j < 4; ++j) sst[t + j * 256] = st[t + j * 256];
    __syncthreads();
    int b = blockIdx.x;
    int e = y[b];
    const float* wp = W5 + (size_t)e * 7680;   // [512][3][5]: c*15 + hw
    const short* hb = h4 + (size_t)b * 7680;   // NHWC: hw*512 + c
    float s = 0.f;
    for (int f = t; f < 7680; f += 256) {
        int c  = f & 511;
        int hw = f >> 9;
        float hv = bf2f(hb[f]);
        hv = fmaf(hv, sst[c], sst[512 + c]);
        hv = fmaxf(hv, SLOPE * hv);
        s = fmaf(hv, wp[c * 15 + hw], s);
    }
    __shared__ float ls[256];
    ls[t] = s; __syncthreads();
    for (int d = 128; d > 0; d >>= 1) {
        if (t < d) ls[t] += ls[t + d];
        __syncthreads();
    }
    if (t == 0) out[b] = ls[0];
}

extern "C" void kernel_launch(void* const* d_in, const int* in_sizes, int n_in,
                              void* d_out, int out_size, void* d_ws, size_t ws_size,
                              hipStream_t stream) {
    const float* x  = (const float*)d_in[0];
    const float* W1 = (const float*)d_in[1];
    const float* g1 = (const float*)d_in[2];
    const float* b1 = (const float*)d_in[3];
    const float* W2 = (const float*)d_in[4];
    const float* g2 = (const float*)d_in[5];
    const float* b2 = (const float*)d_in[6];
    const float* W3 = (const float*)d_in[7];
    const float* g3 = (const float*)d_in[8];
    const float* b3 = (const float*)d_in[9];
    const float* W4 = (const float*)d_in[10];
    const float* g4 = (const float*)d_in[11];
    const float* b4 = (const float*)d_in[12];
    const float* W5 = (const float*)d_in[13];
    const int*   y  = (const int*)d_in[14];
    float* out = (float*)d_out;

    const size_t H1 = (size_t)512 * 24 * 40 * 64;
    const size_t H2 = (size_t)512 * 12 * 20 * 128;
    const size_t H3 = (size_t)512 * 6  * 10 * 256;
    const size_t H4 = (size_t)512 * 3  * 5  * 512;

    float* ws = (float*)d_ws;
    short* h1b = (short*)ws;
    short* h2b = (short*)(ws + H1 / 2);
    short* h3b = (short*)(ws + H1 / 2 + H2 / 2);
    short* h4b = (short*)(ws + H1 / 2 + H2 / 2 + H3 / 2);
    float* fbase = ws + H1 / 2 + H2 / 2 + H3 / 2 + H4 / 2;
    short* wB2 = (short*)fbase;                       // 131072 sh
    short* wB3 = (short*)(fbase + 65536);             // 524288 sh
    short* wB4 = (short*)(fbase + 65536 + 262144);    // 2097152 sh
    float* part = fbase + 65536 + 262144 + 1048576;   // 524288 f
    float* st1 = part + 524288;
    float* st2 = st1 + 128;
    float* st3 = st2 + 256;
    float* st4 = st3 + 512;

    const int NB = 512;

    twkB_k<<<(128 * 64 * 16 + 255) / 256, 256, 0, stream>>>(W2, wB2, 128, 64);
    twkB_k<<<(256 * 128 * 16 + 255) / 256, 256, 0, stream>>>(W3, wB3, 256, 128);
    twkB_k<<<(512 * 256 * 16 + 255) / 256, 256, 0, stream>>>(W4, wB4, 512, 256);

    // ---- L1 ----
    conv1_k<<<1920, 256, 0, stream>>>(x, W1, h1b);
    {
        int R = 512 * 24 * 40, rpb = (R + NB - 1) / NB;
        reduceB_k<64><<<NB, 256, 0, stream>>>(h1b, part, R, rpb);
        stats_k<64><<<1, 64, 0, stream>>>(part, g1, b1, st1, NB, 1.f / R);
        scaleB_k<64><<<2048, 256, 0, stream>>>(h1b, st1, H1 / 8);
    }
    // ---- L2 ----  M=122880 -> 960 tiles, BN=128 (nTN=1)
    convM_k<64, 128, 128, 24, 40, 12, 20><<<960, 256, 0, stream>>>(h1b, wB2, h2b, part);
    {
        float invR = 1.f / (512 * 12 * 20);
        stats2_k<128, 128><<<1, 128, 0, stream>>>(part, g2, b2, st2, 960, invR);
        scaleB_k<128><<<2048, 256, 0, stream>>>(h2b, st2, H2 / 8);
    }
    // ---- L3 ----  M=30720 -> 240 m-tiles x 2 n-tiles, BN=128
    convM_k<128, 256, 128, 12, 20, 6, 10><<<240 * 2, 256, 0, stream>>>(h2b, wB3, h3b, part);
    {
        float invR = 1.f / (512 * 6 * 10);
        stats2_k<256, 128><<<1, 256, 0, stream>>>(part, g3, b3, st3, 240, invR);
        scaleB_k<256><<<2048, 256, 0, stream>>>(h3b, st3, H3 / 8);
    }
    // ---- L4 ----  M=7680 -> 60 m-tiles x 8 n-tiles, BN=64 -> 480 blocks
    convM_k<256, 512, 64, 6, 10, 3, 5><<<60 * 8, 256, 0, stream>>>(h3b, wB4, h4b, part);
    {
        float invR = 1.f / (512 * 3 * 5);
        stats2_k<512, 64><<<1, 512, 0, stream>>>(part, g4, b4, st4, 60, invR);
    }
    // ---- head (st4 fused) ----
    head_k<<<512, 256, 0, stream>>>(h4b, W5, y, st4, out);
}

// Round 5
// 471.380 us; speedup vs baseline: 48.6258x; 1.7406x over previous
//
#include <hip/hip_runtime.h>
#include <hip/hip_bf16.h>
#include <math.h>

#define EPS 1e-5f
#define SLOPE 0.2f

// ---------------------------------------------------------------------------
//  L1: [512,  1,48,80] -> [512, 64,24,40]
//  L2: [512, 64,24,40] -> [512,128,12,20]
//  L3: [512,128,12,20] -> [512,256, 6,10]
//  L4: [512,256, 6,10] -> [512,512, 3, 5]
// bf16 NHWC activations. Conv2-4 = MFMA implicit GEMM (16x16x32 bf16),
// BM=128, BK=32, BN templated (128/128/64), 4 waves. BN stage-1 reduction
// fused into convM epilogue from f32 accumulators. Stage-2 folds are
// 1024-thread [P][C] parallel reductions (round-4 fix: the old C-thread
// serial fold was 228 us on one CU). conv1 = pixel-per-lane.
// ---------------------------------------------------------------------------

typedef short bf16x8 __attribute__((ext_vector_type(8)));
typedef short short4v __attribute__((ext_vector_type(4)));
typedef float f32x4 __attribute__((ext_vector_type(4)));

__device__ __forceinline__ float bf2f(short s) {
    unsigned int u = ((unsigned int)(unsigned short)s) << 16;
    float f;
    __builtin_memcpy(&f, &u, 4);
    return f;
}
__device__ __forceinline__ short f2bf(float f) {
    unsigned int u;
    __builtin_memcpy(&u, &f, 4);
    u = (u + 0x7FFFu + ((u >> 16) & 1u)) >> 16;   // RNE
    return (short)(unsigned short)u;
}

// ---- weight cast+reorder: OIHW fp32 -> bf16 [co][kp*CIN + ci] ----
__global__ __launch_bounds__(256) void twkB_k(const float* __restrict__ W,
                                              short* __restrict__ wB, int O, int I) {
    int idx = blockIdx.x * 256 + threadIdx.x;
    int total = O * I * 16;
    if (idx >= total) return;
    int K = I * 16;
    int co = idx / K;
    int rem = idx % K;
    int kp = rem / I;
    int ci = rem % I;
    wB[idx] = f2bf(W[((size_t)co * I + ci) * 16 + kp]);
}

// ---- conv1: pixel-per-lane, all 64 cout per thread, W1 in LDS ----
__global__ __launch_bounds__(256) void conv1_k(const float* __restrict__ x,
                                               const float* __restrict__ W1,
                                               short* __restrict__ out) {
    __shared__ float wlds[1024];          // W1 [64 co][16 k] fp32
    int t = threadIdx.x;
    ((float4*)wlds)[t] = ((const float4*)W1)[t];
    __syncthreads();

    int pixel = blockIdx.x * 256 + t;     // 512*24*40 = 491520 pixels
    int n  = pixel / 960;
    int p  = pixel % 960;
    int oh = p / 40, ow = p % 40;
    int ih0 = oh * 2 - 1, iw0 = ow * 2 - 1;

    float patch[16];
#pragma unroll
    for (int kh = 0; kh < 4; ++kh) {
        int ih = ih0 + kh;
#pragma unroll
        for (int kw = 0; kw < 4; ++kw) {
            int iw = iw0 + kw;
            bool ok = ((unsigned)ih < 48u) && ((unsigned)iw < 80u);
            patch[kh * 4 + kw] = ok ? x[((size_t)n * 48 + ih) * 80 + iw] : 0.f;
        }
    }
#pragma unroll
    for (int cog = 0; cog < 8; ++cog) {
        bf16x8 v;
#pragma unroll
        for (int j = 0; j < 8; ++j) {
            const float4* wv = (const float4*)(wlds + (cog * 8 + j) * 16);
            float4 w0 = wv[0], w1 = wv[1], w2 = wv[2], w3 = wv[3];
            float a = 0.f;
            a = fmaf(patch[0],  w0.x, a); a = fmaf(patch[1],  w0.y, a);
            a = fmaf(patch[2],  w0.z, a); a = fmaf(patch[3],  w0.w, a);
            a = fmaf(patch[4],  w1.x, a); a = fmaf(patch[5],  w1.y, a);
            a = fmaf(patch[6],  w1.z, a); a = fmaf(patch[7],  w1.w, a);
            a = fmaf(patch[8],  w2.x, a); a = fmaf(patch[9],  w2.y, a);
            a = fmaf(patch[10], w2.z, a); a = fmaf(patch[11], w2.w, a);
            a = fmaf(patch[12], w3.x, a); a = fmaf(patch[13], w3.y, a);
            a = fmaf(patch[14], w3.z, a); a = fmaf(patch[15], w3.w, a);
            v[j] = f2bf(a);
        }
        *(bf16x8*)(out + (size_t)pixel * 64 + cog * 8) = v;
    }
}

// ---- conv2-4: MFMA implicit GEMM + fused BN-partial epilogue ----
template<int CIN, int COUT, int BN, int IH, int IW, int OH, int OW>
__global__ __launch_bounds__(256) void convM_k(const short* __restrict__ in,
                                               const short* __restrict__ wB,   // [COUT][K]
                                               short* __restrict__ out,
                                               float* __restrict__ part) {
    constexpr int K  = CIN * 16;
    constexpr int BM = 128, BK = 32;
    constexpr int NI = BN / 32;                   // ni repeats per wave
    constexpr int LDP = 40;                       // padded row (bf16), 80 B
    __shared__ short As[BM * LDP];
    __shared__ short Bs[BN * LDP];

    const int t = threadIdx.x;
    constexpr int nTN = COUT / BN;
    const int bm = (int)blockIdx.x / nTN, bn = (int)blockIdx.x % nTN;
    const int m0 = bm * BM, n0 = bn * BN;

    // staging coords: thread t -> rows (t>>2 [,+64]), 16B chunk (t&3)
    const int sr = t >> 2, sc = t & 3;
    int pn[2], ph[2], pw[2];
#pragma unroll
    for (int i = 0; i < 2; ++i) {
        int gr = m0 + sr + i * 64;
        int n = gr / (OH * OW), p = gr % (OH * OW);
        pn[i] = n; ph[i] = (p / OW) * 2 - 1; pw[i] = (p % OW) * 2 - 1;
    }
    // 4 waves in 2x2; wave tile 64 x (BN/2)
    const int w = t >> 6, l = t & 63;
    const int wr = (w >> 1) * 64, wc = (w & 1) * (BN / 2);
    const int fr = l & 15, kq = l >> 4;

    f32x4 acc[4][NI];
#pragma unroll
    for (int mi = 0; mi < 4; ++mi)
#pragma unroll
        for (int ni = 0; ni < NI; ++ni) acc[mi][ni] = 0;

    for (int kt = 0; kt < K / BK; ++kt) {
        const int kp = (kt * BK) / CIN, ci0 = (kt * BK) % CIN;
        const int kh = kp >> 2, kw = kp & 3;
        // stage A (predicated boundary)
#pragma unroll
        for (int i = 0; i < 2; ++i) {
            int ih = ph[i] + kh, iw = pw[i] + kw;
            bf16x8 v = 0;
            if ((unsigned)ih < (unsigned)IH && (unsigned)iw < (unsigned)IW)
                v = *(const bf16x8*)(in + (((size_t)pn[i] * IH + ih) * IW + iw) * CIN
                                        + ci0 + sc * 8);
            *(bf16x8*)(As + (sr + i * 64) * LDP + sc * 8) = v;
        }
        // stage B (contiguous rows of wB), BN/64 rows per thread
#pragma unroll
        for (int i = 0; i < BN / 64; ++i) {
            bf16x8 v = *(const bf16x8*)(wB + (size_t)(n0 + sr + i * 64) * K
                                           + kt * BK + sc * 8);
            *(bf16x8*)(Bs + (sr + i * 64) * LDP + sc * 8) = v;
        }
        __syncthreads();

        bf16x8 af[4], bfr[NI];
#pragma unroll
        for (int mi = 0; mi < 4; ++mi)
            af[mi] = *(const bf16x8*)(As + (wr + mi * 16 + fr) * LDP + kq * 8);
#pragma unroll
        for (int ni = 0; ni < NI; ++ni)
            bfr[ni] = *(const bf16x8*)(Bs + (wc + ni * 16 + fr) * LDP + kq * 8);
#pragma unroll
        for (int mi = 0; mi < 4; ++mi)
#pragma unroll
            for (int ni = 0; ni < NI; ++ni)
                acc[mi][ni] = __builtin_amdgcn_mfma_f32_16x16x32_bf16(
                    af[mi], bfr[ni], acc[mi][ni], 0, 0, 0);
        __syncthreads();
    }

    // store raw conv output (D: row = kq*4+reg, col = fr)
#pragma unroll
    for (int mi = 0; mi < 4; ++mi)
#pragma unroll
        for (int ni = 0; ni < NI; ++ni)
#pragma unroll
            for (int r = 0; r < 4; ++r) {
                int row = m0 + wr + mi * 16 + kq * 4 + r;
                int col = n0 + wc + ni * 16 + fr;
                out[(size_t)row * COUT + col] = f2bf(acc[mi][ni][r]);
            }

    // fused BN stage-1: per-block channel partials from f32 accs
    float* red = (float*)As;               // 8 * BN * 2 f32 <= 8 KB, aliases As
#pragma unroll
    for (int ni = 0; ni < NI; ++ni) {
        float s = 0.f, q = 0.f;
#pragma unroll
        for (int mi = 0; mi < 4; ++mi)
#pragma unroll
            for (int r = 0; r < 4; ++r) {
                float v = acc[mi][ni][r];
                s += v; q = fmaf(v, v, q);
            }
        int slot = (w >> 1) * 4 + kq;      // 0..7
        int ch = wc + ni * 16 + fr;        // 0..BN-1
        red[(slot * BN + ch) * 2 + 0] = s;
        red[(slot * BN + ch) * 2 + 1] = q;
    }
    __syncthreads();
    if (t < BN) {
        float s = 0.f, q = 0.f;
#pragma unroll
        for (int slot = 0; slot < 8; ++slot) {
            s += red[(slot * BN + t) * 2 + 0];
            q += red[(slot * BN + t) * 2 + 1];
        }
        part[(size_t)blockIdx.x * (2 * BN) + t]      = s;
        part[(size_t)blockIdx.x * (2 * BN) + BN + t] = q;
    }
}

// ---- BN stats stage 1 for h1 (bf16 input) ----
template<int C>
__global__ __launch_bounds__(256) void reduceB_k(const short* __restrict__ h,
                                                 float* __restrict__ part,
                                                 int R, int rpb) {
    constexpr int CG = C / 4;
    constexpr int STEP = 256 / CG;
    int t = threadIdx.x;
    int c4 = t % CG, rsub = t / CG;
    int r_lo = blockIdx.x * rpb, r_hi = min(R, r_lo + rpb);
    float s[4] = {0, 0, 0, 0}, q[4] = {0, 0, 0, 0};
    for (int r = r_lo + rsub; r < r_hi; r += STEP) {
        short4v v = *(const short4v*)(h + (size_t)r * C + c4 * 4);
#pragma unroll
        for (int j = 0; j < 4; ++j) { float f = bf2f(v[j]); s[j] += f; q[j] += f * f; }
    }
    __shared__ float ls[4][256], lq[4][256];
#pragma unroll
    for (int j = 0; j < 4; ++j) { ls[j][t] = s[j]; lq[j][t] = q[j]; }
    __syncthreads();
    for (int d = 128; d >= CG; d >>= 1) {
        if (t < d) {
#pragma unroll
            for (int j = 0; j < 4; ++j) { ls[j][t] += ls[j][t + d]; lq[j][t] += lq[j][t + d]; }
        }
        __syncthreads();
    }
    if (t < CG) {
#pragma unroll
        for (int j = 0; j < 4; ++j) {
            part[(size_t)blockIdx.x * 2 * C + c4 * 4 + j]     = ls[j][t];
            part[(size_t)blockIdx.x * 2 * C + C + c4 * 4 + j] = lq[j][t];
        }
    }
}

// ---- parallel stage-2 fold, reduceB layout (stride 2C per block) ----
// blockDim = C*P (<=1024); thread (j,c) sums blocks j, j+P, ...
template<int C, int P>
__global__ __launch_bounds__(1024) void statsP_k(const float* __restrict__ part,
                                                 const float* __restrict__ gamma,
                                                 const float* __restrict__ beta,
                                                 float* __restrict__ st,
                                                 int nblocks, float invR) {
    int t = threadIdx.x;
    int c = t % C, j = t / C;
    float s = 0.f, q = 0.f;
    for (int b = j; b < nblocks; b += P) {
        s += part[(size_t)b * 2 * C + c];
        q += part[(size_t)b * 2 * C + C + c];
    }
    __shared__ float ls[1024], lq[1024];
    ls[t] = s; lq[t] = q; __syncthreads();
    for (int d = C * P / 2; d >= C; d >>= 1) {
        if (t < d) { ls[t] += ls[t + d]; lq[t] += lq[t + d]; }
        __syncthreads();
    }
    if (t < C) {
        float mean = ls[t] * invR;
        float var  = lq[t] * invR - mean * mean;
        float sc = gamma[t] * rsqrtf(var + EPS);
        st[t]     = sc;
        st[C + t] = beta[t] - mean * sc;
    }
}

// ---- parallel stage-2 fold, convM-epilogue layout ----
// part blocks laid out [bm][bn] with 2*BN floats each; blockDim = C*P.
template<int C, int BN, int P>
__global__ __launch_bounds__(1024) void stats2P_k(const float* __restrict__ part,
                                                  const float* __restrict__ gamma,
                                                  const float* __restrict__ beta,
                                                  float* __restrict__ st,
                                                  int nTM, float invR) {
    constexpr int NTN = C / BN;
    int t = threadIdx.x;
    int c = t % C, j = t / C;
    int bn = c / BN, cc = c % BN;
    float s = 0.f, q = 0.f;
    for (int bm = j; bm < nTM; bm += P) {
        size_t idx = (size_t)(bm * NTN + bn) * (2 * BN);
        s += part[idx + cc];
        q += part[idx + BN + cc];
    }
    __shared__ float ls[1024], lq[1024];
    ls[t] = s; lq[t] = q; __syncthreads();
    for (int d = C * P / 2; d >= C; d >>= 1) {
        if (t < d) { ls[t] += ls[t + d]; lq[t] += lq[t + d]; }
        __syncthreads();
    }
    if (t < C) {
        float mean = ls[t] * invR;
        float var  = lq[t] * invR - mean * mean;
        float sc = gamma[t] * rsqrtf(var + EPS);
        st[t]     = sc;
        st[C + t] = beta[t] - mean * sc;
    }
}

// ---- in-place bf16 normalize + LeakyReLU ----
template<int C>
__global__ __launch_bounds__(256) void scaleB_k(short* __restrict__ h,
                                                const float* __restrict__ st,
                                                size_t n8) {
    __shared__ float sst[1024];
    int t = threadIdx.x;
    for (int j = t; j < 2 * C; j += 256) sst[j] = st[j];
    __syncthreads();
    size_t i = (size_t)blockIdx.x * 256 + t;
    size_t stride = (size_t)gridDim.x * 256;
    bf16x8* h8 = (bf16x8*)h;
    for (; i < n8; i += stride) {
        bf16x8 v = h8[i];
        int c0 = (int)((i * 8) & (size_t)(C - 1));
#pragma unroll
        for (int j = 0; j < 8; ++j) {
            float f = bf2f(v[j]);
            f = fmaf(f, sst[c0 + j], sst[C + c0 + j]);
            f = fmaxf(f, SLOPE * f);
            v[j] = f2bf(f);
        }
        h8[i] = v;
    }
}

// ---- expert head with fused st4 normalize+lrelu ----
__global__ __launch_bounds__(256) void head_k(const short* __restrict__ h4,
                                              const float* __restrict__ W5,
                                              const int* __restrict__ y,
                                              const float* __restrict__ st,
                                              float* __restrict__ out) {
    __shared__ float sst[1024];
    int t = threadIdx.x;
#pragma unroll
    for (int j = 0; j < 4; ++j) sst[t + j * 256] = st[t + j * 256];
    __syncthreads();
    int b = blockIdx.x;
    int e = y[b];
    const float* wp = W5 + (size_t)e * 7680;   // [512][3][5]: c*15 + hw
    const short* hb = h4 + (size_t)b * 7680;   // NHWC: hw*512 + c
    float s = 0.f;
    for (int f = t; f < 7680; f += 256) {
        int c  = f & 511;
        int hw = f >> 9;
        float hv = bf2f(hb[f]);
        hv = fmaf(hv, sst[c], sst[512 + c]);
        hv = fmaxf(hv, SLOPE * hv);
        s = fmaf(hv, wp[c * 15 + hw], s);
    }
    __shared__ float ls[256];
    ls[t] = s; __syncthreads();
    for (int d = 128; d > 0; d >>= 1) {
        if (t < d) ls[t] += ls[t + d];
        __syncthreads();
    }
    if (t == 0) out[b] = ls[0];
}

extern "C" void kernel_launch(void* const* d_in, const int* in_sizes, int n_in,
                              void* d_out, int out_size, void* d_ws, size_t ws_size,
                              hipStream_t stream) {
    const float* x  = (const float*)d_in[0];
    const float* W1 = (const float*)d_in[1];
    const float* g1 = (const float*)d_in[2];
    const float* b1 = (const float*)d_in[3];
    const float* W2 = (const float*)d_in[4];
    const float* g2 = (const float*)d_in[5];
    const float* b2 = (const float*)d_in[6];
    const float* W3 = (const float*)d_in[7];
    const float* g3 = (const float*)d_in[8];
    const float* b3 = (const float*)d_in[9];
    const float* W4 = (const float*)d_in[10];
    const float* g4 = (const float*)d_in[11];
    const float* b4 = (const float*)d_in[12];
    const float* W5 = (const float*)d_in[13];
    const int*   y  = (const int*)d_in[14];
    float* out = (float*)d_out;

    const size_t H1 = (size_t)512 * 24 * 40 * 64;
    const size_t H2 = (size_t)512 * 12 * 20 * 128;
    const size_t H3 = (size_t)512 * 6  * 10 * 256;
    const size_t H4 = (size_t)512 * 3  * 5  * 512;

    float* ws = (float*)d_ws;
    short* h1b = (short*)ws;
    short* h2b = (short*)(ws + H1 / 2);
    short* h3b = (short*)(ws + H1 / 2 + H2 / 2);
    short* h4b = (short*)(ws + H1 / 2 + H2 / 2 + H3 / 2);
    float* fbase = ws + H1 / 2 + H2 / 2 + H3 / 2 + H4 / 2;
    short* wB2 = (short*)fbase;                       // 131072 sh
    short* wB3 = (short*)(fbase + 65536);             // 524288 sh
    short* wB4 = (short*)(fbase + 65536 + 262144);    // 2097152 sh
    float* part = fbase + 65536 + 262144 + 1048576;   // 524288 f
    float* st1 = part + 524288;
    float* st2 = st1 + 128;
    float* st3 = st2 + 256;
    float* st4 = st3 + 512;

    const int NB = 512;

    twkB_k<<<(128 * 64 * 16 + 255) / 256, 256, 0, stream>>>(W2, wB2, 128, 64);
    twkB_k<<<(256 * 128 * 16 + 255) / 256, 256, 0, stream>>>(W3, wB3, 256, 128);
    twkB_k<<<(512 * 256 * 16 + 255) / 256, 256, 0, stream>>>(W4, wB4, 512, 256);

    // ---- L1 ----
    conv1_k<<<1920, 256, 0, stream>>>(x, W1, h1b);
    {
        int R = 512 * 24 * 40, rpb = (R + NB - 1) / NB;
        reduceB_k<64><<<NB, 256, 0, stream>>>(h1b, part, R, rpb);
        statsP_k<64, 16><<<1, 1024, 0, stream>>>(part, g1, b1, st1, NB, 1.f / R);
        scaleB_k<64><<<2048, 256, 0, stream>>>(h1b, st1, H1 / 8);
    }
    // ---- L2 ----  M=122880 -> 960 tiles, BN=128 (nTN=1)
    convM_k<64, 128, 128, 24, 40, 12, 20><<<960, 256, 0, stream>>>(h1b, wB2, h2b, part);
    {
        float invR = 1.f / (512 * 12 * 20);
        stats2P_k<128, 128, 8><<<1, 1024, 0, stream>>>(part, g2, b2, st2, 960, invR);
        scaleB_k<128><<<2048, 256, 0, stream>>>(h2b, st2, H2 / 8);
    }
    // ---- L3 ----  M=30720 -> 240 m-tiles x 2 n-tiles, BN=128
    convM_k<128, 256, 128, 12, 20, 6, 10><<<240 * 2, 256, 0, stream>>>(h2b, wB3, h3b, part);
    {
        float invR = 1.f / (512 * 6 * 10);
        stats2P_k<256, 128, 4><<<1, 1024, 0, stream>>>(part, g3, b3, st3, 240, invR);
        scaleB_k<256><<<2048, 256, 0, stream>>>(h3b, st3, H3 / 8);
    }
    // ---- L4 ----  M=7680 -> 60 m-tiles x 8 n-tiles, BN=64 -> 480 blocks
    convM_k<256, 512, 64, 6, 10, 3, 5><<<60 * 8, 256, 0, stream>>>(h3b, wB4, h4b, part);
    {
        float invR = 1.f / (512 * 3 * 5);
        stats2P_k<512, 64, 2><<<1, 1024, 0, stream>>>(part, g4, b4, st4, 60, invR);
    }
    // ---- head (st4 fused) ----
    head_k<<<512, 256, 0, stream>>>(h4b, W5, y, st4, out);
}

// Round 6
// 430.314 us; speedup vs baseline: 53.2662x; 1.0954x over previous
//
#include <hip/hip_runtime.h>
#include <hip/hip_bf16.h>
#include <math.h>

#define EPS 1e-5f
#define SLOPE 0.2f

// ---------------------------------------------------------------------------
//  L1: [512,  1,48,80] -> [512, 64,24,40]
//  L2: [512, 64,24,40] -> [512,128,12,20]
//  L3: [512,128,12,20] -> [512,256, 6,10]
//  L4: [512,256, 6,10] -> [512,512, 3, 5]
// bf16 NHWC. Conv2-4 = MFMA implicit GEMM, BM=128 BN=64 BK=64, XOR-swizzled
// LDS (conflict-free), reg-prefetch 2-phase pipeline, split-K (1/2/4) so all
// layers run 1920 blocks x 16 K-iterations. KS>1 writes f32 partials; combC
// sums them, emits bf16 + BN stage-1 partials. Stage-2 folds are 1024-thread
// parallel reductions.
// ---------------------------------------------------------------------------

typedef short bf16x8 __attribute__((ext_vector_type(8)));
typedef short short4v __attribute__((ext_vector_type(4)));
typedef float f32x4 __attribute__((ext_vector_type(4)));

__device__ __forceinline__ float bf2f(short s) {
    unsigned int u = ((unsigned int)(unsigned short)s) << 16;
    float f;
    __builtin_memcpy(&f, &u, 4);
    return f;
}
__device__ __forceinline__ short f2bf(float f) {
    unsigned int u;
    __builtin_memcpy(&u, &f, 4);
    u = (u + 0x7FFFu + ((u >> 16) & 1u)) >> 16;   // RNE
    return (short)(unsigned short)u;
}

// ---- weight cast+reorder: OIHW fp32 -> bf16 [co][kp*CIN + ci] ----
__global__ __launch_bounds__(256) void twkB_k(const float* __restrict__ W,
                                              short* __restrict__ wB, int O, int I) {
    int idx = blockIdx.x * 256 + threadIdx.x;
    int total = O * I * 16;
    if (idx >= total) return;
    int K = I * 16;
    int co = idx / K;
    int rem = idx % K;
    int kp = rem / I;
    int ci = rem % I;
    wB[idx] = f2bf(W[((size_t)co * I + ci) * 16 + kp]);
}

// ---- conv1: pixel-per-lane, all 64 cout per thread, W1 in LDS ----
__global__ __launch_bounds__(256) void conv1_k(const float* __restrict__ x,
                                               const float* __restrict__ W1,
                                               short* __restrict__ out) {
    __shared__ float wlds[1024];          // W1 [64 co][16 k] fp32
    int t = threadIdx.x;
    ((float4*)wlds)[t] = ((const float4*)W1)[t];
    __syncthreads();

    int pixel = blockIdx.x * 256 + t;     // 512*24*40 = 491520 pixels
    int n  = pixel / 960;
    int p  = pixel % 960;
    int oh = p / 40, ow = p % 40;
    int ih0 = oh * 2 - 1, iw0 = ow * 2 - 1;

    float patch[16];
#pragma unroll
    for (int kh = 0; kh < 4; ++kh) {
        int ih = ih0 + kh;
#pragma unroll
        for (int kw = 0; kw < 4; ++kw) {
            int iw = iw0 + kw;
            bool ok = ((unsigned)ih < 48u) && ((unsigned)iw < 80u);
            patch[kh * 4 + kw] = ok ? x[((size_t)n * 48 + ih) * 80 + iw] : 0.f;
        }
    }
#pragma unroll
    for (int cog = 0; cog < 8; ++cog) {
        bf16x8 v;
#pragma unroll
        for (int j = 0; j < 8; ++j) {
            const float4* wv = (const float4*)(wlds + (cog * 8 + j) * 16);
            float4 w0 = wv[0], w1 = wv[1], w2 = wv[2], w3 = wv[3];
            float a = 0.f;
            a = fmaf(patch[0],  w0.x, a); a = fmaf(patch[1],  w0.y, a);
            a = fmaf(patch[2],  w0.z, a); a = fmaf(patch[3],  w0.w, a);
            a = fmaf(patch[4],  w1.x, a); a = fmaf(patch[5],  w1.y, a);
            a = fmaf(patch[6],  w1.z, a); a = fmaf(patch[7],  w1.w, a);
            a = fmaf(patch[8],  w2.x, a); a = fmaf(patch[9],  w2.y, a);
            a = fmaf(patch[10], w2.z, a); a = fmaf(patch[11], w2.w, a);
            a = fmaf(patch[12], w3.x, a); a = fmaf(patch[13], w3.y, a);
            a = fmaf(patch[14], w3.z, a); a = fmaf(patch[15], w3.w, a);
            v[j] = f2bf(a);
        }
        *(bf16x8*)(out + (size_t)pixel * 64 + cog * 8) = v;
    }
}

// ---- conv2-4: MFMA implicit GEMM, split-K, XOR-swizzled LDS, reg-prefetch ----
// Grid: bid = ((bm * nTN) + bn) * KS + ks. KS==1: bf16 out + fused BN partials
// (part layout: 2*64 per block). KS>1: f32 partials to pc[ks].
template<int CIN, int COUT, int KS, int IH, int IW, int OH, int OW>
__global__ __launch_bounds__(256, 4) void convM_k(const short* __restrict__ in,
                                                  const short* __restrict__ wB,
                                                  short* __restrict__ out,
                                                  float* __restrict__ pc,
                                                  float* __restrict__ part) {
    constexpr int K  = CIN * 16;
    constexpr int Kc = K / KS;            // 1024 for all layers
    constexpr int NT = Kc / 64;           // 16
    constexpr int BM = 128, BN = 64;
    constexpr size_t MN = (size_t)512 * OH * OW * COUT;
    __shared__ short As[BM * 64];         // 16 KB, swizzled
    __shared__ short Bs[BN * 64];         //  8 KB, swizzled

    const int t = threadIdx.x;
    constexpr int nTN = COUT / BN;
    int bid = (int)blockIdx.x;
    const int ks = bid % KS; bid /= KS;
    const int bn = bid % nTN;
    const int bm = bid / nTN;
    const int m0 = bm * BM, n0 = bn * BN;
    const int k0 = ks * Kc;

    const int cc = t & 7;                 // 16B chunk id within a 64-elem row
    // A staging rows (4 per thread), pixel coords precomputed
    int prow[4], pih[4], piw[4], pbase[4];
#pragma unroll
    for (int i = 0; i < 4; ++i) {
        int row = (t + i * 256) >> 3;
        int gr = m0 + row;
        int n = gr / (OH * OW), p = gr % (OH * OW);
        int oh = p / OW, ow = p % OW;
        prow[i] = row;
        pih[i] = oh * 2 - 1; piw[i] = ow * 2 - 1;
        pbase[i] = n * IH * IW;
    }
    const int brow0 = t >> 3;             // B rows: brow0, brow0+32
    // wave fragment mapping: 4 waves 2x2, wave tile 64x32
    const int w = t >> 6, l = t & 63;
    const int wr = (w >> 1) * 64, wc = (w & 1) * 32;
    const int fr = l & 15, kq = l >> 4;

    f32x4 acc[4][2];
#pragma unroll
    for (int mi = 0; mi < 4; ++mi)
#pragma unroll
        for (int ni = 0; ni < 2; ++ni) acc[mi][ni] = 0;

    bf16x8 ra[4], rb[2];
    auto LOADK = [&](int kt) {
        int kk0 = k0 + kt * 64;
        int kp = kk0 / CIN, ci0 = kk0 % CIN;
        int kh = kp >> 2, kw = kp & 3;
#pragma unroll
        for (int i = 0; i < 4; ++i) {
            int ih = pih[i] + kh, iw = piw[i] + kw;
            bf16x8 v = 0;
            if ((unsigned)ih < (unsigned)IH && (unsigned)iw < (unsigned)IW)
                v = *(const bf16x8*)(in + (size_t)(pbase[i] + ih * IW + iw) * CIN
                                        + ci0 + cc * 8);
            ra[i] = v;
        }
#pragma unroll
        for (int i = 0; i < 2; ++i)
            rb[i] = *(const bf16x8*)(wB + (size_t)(n0 + brow0 + i * 32) * K
                                        + kk0 + cc * 8);
    };

    LOADK(0);
    for (int kt = 0; kt < NT; ++kt) {
        __syncthreads();                  // all waves done reading LDS (prev kt)
#pragma unroll
        for (int i = 0; i < 4; ++i) {
            int row = prow[i];
            *(bf16x8*)(As + row * 64 + ((cc ^ (row & 7)) * 8)) = ra[i];
        }
#pragma unroll
        for (int i = 0; i < 2; ++i) {
            int row = brow0 + i * 32;
            *(bf16x8*)(Bs + row * 64 + ((cc ^ (row & 7)) * 8)) = rb[i];
        }
        LOADK(kt + 1 < NT ? kt + 1 : kt); // prefetch overlaps compute phase
        __syncthreads();                  // LDS ready
#pragma unroll
        for (int kk = 0; kk < 2; ++kk) {
            bf16x8 af[4], bfr[2];
#pragma unroll
            for (int mi = 0; mi < 4; ++mi) {
                int row = wr + mi * 16 + fr;
                af[mi] = *(const bf16x8*)(As + row * 64 + (((kk * 4 + kq) ^ (row & 7)) * 8));
            }
#pragma unroll
            for (int ni = 0; ni < 2; ++ni) {
                int row = wc + ni * 16 + fr;
                bfr[ni] = *(const bf16x8*)(Bs + row * 64 + (((kk * 4 + kq) ^ (row & 7)) * 8));
            }
#pragma unroll
            for (int mi = 0; mi < 4; ++mi)
#pragma unroll
                for (int ni = 0; ni < 2; ++ni)
                    acc[mi][ni] = __builtin_amdgcn_mfma_f32_16x16x32_bf16(
                        af[mi], bfr[ni], acc[mi][ni], 0, 0, 0);
        }
    }

    if constexpr (KS == 1) {
        // bf16 output (D: row = kq*4+r, col = fr) + fused BN stage-1
#pragma unroll
        for (int mi = 0; mi < 4; ++mi)
#pragma unroll
            for (int ni = 0; ni < 2; ++ni)
#pragma unroll
                for (int r = 0; r < 4; ++r) {
                    int row = m0 + wr + mi * 16 + kq * 4 + r;
                    int col = n0 + wc + ni * 16 + fr;
                    out[(size_t)row * COUT + col] = f2bf(acc[mi][ni][r]);
                }
        __syncthreads();                  // done reading As before aliasing
        float* red = (float*)As;          // 8 slots * 64 ch * 2 = 4 KB
#pragma unroll
        for (int ni = 0; ni < 2; ++ni) {
            float s = 0.f, q = 0.f;
#pragma unroll
            for (int mi = 0; mi < 4; ++mi)
#pragma unroll
                for (int r = 0; r < 4; ++r) {
                    float v = acc[mi][ni][r];
                    s += v; q = fmaf(v, v, q);
                }
            int slot = (w >> 1) * 4 + kq;
            int ch = wc + ni * 16 + fr;
            red[(slot * 64 + ch) * 2 + 0] = s;
            red[(slot * 64 + ch) * 2 + 1] = q;
        }
        __syncthreads();
        if (t < 64) {
            float s = 0.f, q = 0.f;
#pragma unroll
            for (int slot = 0; slot < 8; ++slot) {
                s += red[(slot * 64 + t) * 2 + 0];
                q += red[(slot * 64 + t) * 2 + 1];
            }
            part[(size_t)blockIdx.x * 128 + t]      = s;
            part[(size_t)blockIdx.x * 128 + 64 + t] = q;
        }
    } else {
        float* base = pc + (size_t)ks * MN;
#pragma unroll
        for (int mi = 0; mi < 4; ++mi)
#pragma unroll
            for (int ni = 0; ni < 2; ++ni)
#pragma unroll
                for (int r = 0; r < 4; ++r) {
                    int row = m0 + wr + mi * 16 + kq * 4 + r;
                    int col = n0 + wc + ni * 16 + fr;
                    base[(size_t)row * COUT + col] = acc[mi][ni][r];
                }
    }
}

// ---- combine split-K partials: sum KS f32 buffers -> bf16 + BN partials ----
template<int C, int KS>
__global__ __launch_bounds__(256) void combC_k(const float* __restrict__ pc,
                                               short* __restrict__ hout,
                                               float* __restrict__ part,
                                               int R, int rpb, size_t MN) {
    constexpr int CG = C / 4;
    constexpr int STEP = 256 / CG;
    int t = threadIdx.x;
    int c4 = t % CG, rsub = t / CG;
    int r_lo = blockIdx.x * rpb, r_hi = min(R, r_lo + rpb);
    float s[4] = {0, 0, 0, 0}, q[4] = {0, 0, 0, 0};
    for (int r = r_lo + rsub; r < r_hi; r += STEP) {
        float a0 = 0.f, a1 = 0.f, a2 = 0.f, a3 = 0.f;
#pragma unroll
        for (int ks = 0; ks < KS; ++ks) {
            float4 v = *(const float4*)(pc + (size_t)ks * MN + (size_t)r * C + c4 * 4);
            a0 += v.x; a1 += v.y; a2 += v.z; a3 += v.w;
        }
        short4v o;
        o[0] = f2bf(a0); o[1] = f2bf(a1); o[2] = f2bf(a2); o[3] = f2bf(a3);
        *(short4v*)(hout + (size_t)r * C + c4 * 4) = o;
        s[0] += a0; q[0] += a0 * a0; s[1] += a1; q[1] += a1 * a1;
        s[2] += a2; q[2] += a2 * a2; s[3] += a3; q[3] += a3 * a3;
    }
    __shared__ float ls[4][256], lq[4][256];
#pragma unroll
    for (int j = 0; j < 4; ++j) { ls[j][t] = s[j]; lq[j][t] = q[j]; }
    __syncthreads();
    for (int d = 128; d >= CG; d >>= 1) {
        if (t < d) {
#pragma unroll
            for (int j = 0; j < 4; ++j) { ls[j][t] += ls[j][t + d]; lq[j][t] += lq[j][t + d]; }
        }
        __syncthreads();
    }
    if (t < CG) {
#pragma unroll
        for (int j = 0; j < 4; ++j) {
            part[(size_t)blockIdx.x * 2 * C + c4 * 4 + j]     = ls[j][t];
            part[(size_t)blockIdx.x * 2 * C + C + c4 * 4 + j] = lq[j][t];
        }
    }
}

// ---- BN stats stage 1 for h1 (bf16 input) ----
template<int C>
__global__ __launch_bounds__(256) void reduceB_k(const short* __restrict__ h,
                                                 float* __restrict__ part,
                                                 int R, int rpb) {
    constexpr int CG = C / 4;
    constexpr int STEP = 256 / CG;
    int t = threadIdx.x;
    int c4 = t % CG, rsub = t / CG;
    int r_lo = blockIdx.x * rpb, r_hi = min(R, r_lo + rpb);
    float s[4] = {0, 0, 0, 0}, q[4] = {0, 0, 0, 0};
    for (int r = r_lo + rsub; r < r_hi; r += STEP) {
        short4v v = *(const short4v*)(h + (size_t)r * C + c4 * 4);
#pragma unroll
        for (int j = 0; j < 4; ++j) { float f = bf2f(v[j]); s[j] += f; q[j] += f * f; }
    }
    __shared__ float ls[4][256], lq[4][256];
#pragma unroll
    for (int j = 0; j < 4; ++j) { ls[j][t] = s[j]; lq[j][t] = q[j]; }
    __syncthreads();
    for (int d = 128; d >= CG; d >>= 1) {
        if (t < d) {
#pragma unroll
            for (int j = 0; j < 4; ++j) { ls[j][t] += ls[j][t + d]; lq[j][t] += lq[j][t + d]; }
        }
        __syncthreads();
    }
    if (t < CG) {
#pragma unroll
        for (int j = 0; j < 4; ++j) {
            part[(size_t)blockIdx.x * 2 * C + c4 * 4 + j]     = ls[j][t];
            part[(size_t)blockIdx.x * 2 * C + C + c4 * 4 + j] = lq[j][t];
        }
    }
}

// ---- parallel stage-2 fold, reduceB/combC layout (stride 2C per block) ----
template<int C, int P>
__global__ __launch_bounds__(1024) void statsP_k(const float* __restrict__ part,
                                                 const float* __restrict__ gamma,
                                                 const float* __restrict__ beta,
                                                 float* __restrict__ st,
                                                 int nblocks, float invR) {
    int t = threadIdx.x;
    int c = t % C, j = t / C;
    float s = 0.f, q = 0.f;
    for (int b = j; b < nblocks; b += P) {
        s += part[(size_t)b * 2 * C + c];
        q += part[(size_t)b * 2 * C + C + c];
    }
    __shared__ float ls[1024], lq[1024];
    ls[t] = s; lq[t] = q; __syncthreads();
    for (int d = C * P / 2; d >= C; d >>= 1) {
        if (t < d) { ls[t] += ls[t + d]; lq[t] += lq[t + d]; }
        __syncthreads();
    }
    if (t < C) {
        float mean = ls[t] * invR;
        float var  = lq[t] * invR - mean * mean;
        float sc = gamma[t] * rsqrtf(var + EPS);
        st[t]     = sc;
        st[C + t] = beta[t] - mean * sc;
    }
}

// ---- parallel stage-2 fold, convM fused-epilogue layout (2*64 per block) ----
template<int C, int BNp, int P>
__global__ __launch_bounds__(1024) void stats2P_k(const float* __restrict__ part,
                                                  const float* __restrict__ gamma,
                                                  const float* __restrict__ beta,
                                                  float* __restrict__ st,
                                                  int nTM, float invR) {
    constexpr int NTN = C / BNp;
    int t = threadIdx.x;
    int c = t % C, j = t / C;
    int bn = c / BNp, cc = c % BNp;
    float s = 0.f, q = 0.f;
    for (int bm = j; bm < nTM; bm += P) {
        size_t idx = (size_t)(bm * NTN + bn) * (2 * BNp);
        s += part[idx + cc];
        q += part[idx + BNp + cc];
    }
    __shared__ float ls[1024], lq[1024];
    ls[t] = s; lq[t] = q; __syncthreads();
    for (int d = C * P / 2; d >= C; d >>= 1) {
        if (t < d) { ls[t] += ls[t + d]; lq[t] += lq[t + d]; }
        __syncthreads();
    }
    if (t < C) {
        float mean = ls[t] * invR;
        float var  = lq[t] * invR - mean * mean;
        float sc = gamma[t] * rsqrtf(var + EPS);
        st[t]     = sc;
        st[C + t] = beta[t] - mean * sc;
    }
}

// ---- in-place bf16 normalize + LeakyReLU ----
template<int C>
__global__ __launch_bounds__(256) void scaleB_k(short* __restrict__ h,
                                                const float* __restrict__ st,
                                                size_t n8) {
    __shared__ float sst[1024];
    int t = threadIdx.x;
    for (int j = t; j < 2 * C; j += 256) sst[j] = st[j];
    __syncthreads();
    size_t i = (size_t)blockIdx.x * 256 + t;
    size_t stride = (size_t)gridDim.x * 256;
    bf16x8* h8 = (bf16x8*)h;
    for (; i < n8; i += stride) {
        bf16x8 v = h8[i];
        int c0 = (int)((i * 8) & (size_t)(C - 1));
#pragma unroll
        for (int j = 0; j < 8; ++j) {
            float f = bf2f(v[j]);
            f = fmaf(f, sst[c0 + j], sst[C + c0 + j]);
            f = fmaxf(f, SLOPE * f);
            v[j] = f2bf(f);
        }
        h8[i] = v;
    }
}

// ---- expert head with fused st4 normalize+lrelu ----
__global__ __launch_bounds__(256) void head_k(const short* __restrict__ h4,
                                              const float* __restrict__ W5,
                                              const int* __restrict__ y,
                                              const float* __restrict__ st,
                                              float* __restrict__ out) {
    __shared__ float sst[1024];
    int t = threadIdx.x;
#pragma unroll
    for (int j = 0; j < 4; ++j) sst[t + j * 256] = st[t + j * 256];
    __syncthreads();
    int b = blockIdx.x;
    int e = y[b];
    const float* wp = W5 + (size_t)e * 7680;   // [512][3][5]: c*15 + hw
    const short* hb = h4 + (size_t)b * 7680;   // NHWC: hw*512 + c
    float s = 0.f;
    for (int f = t; f < 7680; f += 256) {
        int c  = f & 511;
        int hw = f >> 9;
        float hv = bf2f(hb[f]);
        hv = fmaf(hv, sst[c], sst[512 + c]);
        hv = fmaxf(hv, SLOPE * hv);
        s = fmaf(hv, wp[c * 15 + hw], s);
    }
    __shared__ float ls[256];
    ls[t] = s; __syncthreads();
    for (int d = 128; d > 0; d >>= 1) {
        if (t < d) ls[t] += ls[t + d];
        __syncthreads();
    }
    if (t == 0) out[b] = ls[0];
}

extern "C" void kernel_launch(void* const* d_in, const int* in_sizes, int n_in,
                              void* d_out, int out_size, void* d_ws, size_t ws_size,
                              hipStream_t stream) {
    const float* x  = (const float*)d_in[0];
    const float* W1 = (const float*)d_in[1];
    const float* g1 = (const float*)d_in[2];
    const float* b1 = (const float*)d_in[3];
    const float* W2 = (const float*)d_in[4];
    const float* g2 = (const float*)d_in[5];
    const float* b2 = (const float*)d_in[6];
    const float* W3 = (const float*)d_in[7];
    const float* g3 = (const float*)d_in[8];
    const float* b3 = (const float*)d_in[9];
    const float* W4 = (const float*)d_in[10];
    const float* g4 = (const float*)d_in[11];
    const float* b4 = (const float*)d_in[12];
    const float* W5 = (const float*)d_in[13];
    const int*   y  = (const int*)d_in[14];
    float* out = (float*)d_out;

    const size_t H1 = (size_t)512 * 24 * 40 * 64;
    const size_t H2 = (size_t)512 * 12 * 20 * 128;
    const size_t H3 = (size_t)512 * 6  * 10 * 256;
    const size_t H4 = (size_t)512 * 3  * 5  * 512;

    float* ws = (float*)d_ws;
    short* h1b = (short*)ws;
    short* h2b = (short*)(ws + H1 / 2);
    short* h3b = (short*)(ws + H1 / 2 + H2 / 2);
    short* h4b = (short*)(ws + H1 / 2 + H2 / 2 + H3 / 2);
    float* fbase = ws + H1 / 2 + H2 / 2 + H3 / 2 + H4 / 2;
    short* wB2 = (short*)fbase;                       // 131072 sh
    short* wB3 = (short*)(fbase + 65536);             // 524288 sh
    short* wB4 = (short*)(fbase + 65536 + 262144);    // 2097152 sh
    float* part = fbase + 65536 + 262144 + 1048576;   // 524288 f
    float* st1 = part + 524288;
    float* st2 = st1 + 128;
    float* st3 = st2 + 256;
    float* st4 = st3 + 512;
    float* pc  = st4 + 1024;                          // 15,728,640 f (63 MB)

    const int NB = 512;

    twkB_k<<<(128 * 64 * 16 + 255) / 256, 256, 0, stream>>>(W2, wB2, 128, 64);
    twkB_k<<<(256 * 128 * 16 + 255) / 256, 256, 0, stream>>>(W3, wB3, 256, 128);
    twkB_k<<<(512 * 256 * 16 + 255) / 256, 256, 0, stream>>>(W4, wB4, 512, 256);

    // ---- L1 ----
    conv1_k<<<1920, 256, 0, stream>>>(x, W1, h1b);
    {
        int R = 512 * 24 * 40, rpb = (R + NB - 1) / NB;
        reduceB_k<64><<<NB, 256, 0, stream>>>(h1b, part, R, rpb);
        statsP_k<64, 16><<<1, 1024, 0, stream>>>(part, g1, b1, st1, NB, 1.f / R);
        scaleB_k<64><<<2048, 256, 0, stream>>>(h1b, st1, H1 / 8);
    }
    // ---- L2 ----  960 m x 2 n x KS1 = 1920 blocks, fused BN partials
    convM_k<64, 128, 1, 24, 40, 12, 20><<<1920, 256, 0, stream>>>(h1b, wB2, h2b, pc, part);
    {
        float invR = 1.f / (512 * 12 * 20);
        stats2P_k<128, 64, 8><<<1, 1024, 0, stream>>>(part, g2, b2, st2, 960, invR);
        scaleB_k<128><<<2048, 256, 0, stream>>>(h2b, st2, H2 / 8);
    }
    // ---- L3 ----  240 m x 4 n x KS2 = 1920 blocks -> combine
    convM_k<128, 256, 2, 12, 20, 6, 10><<<1920, 256, 0, stream>>>(h2b, wB3, h3b, pc, part);
    {
        int R = 512 * 6 * 10;                          // 30720 rows
        combC_k<256, 2><<<240, 256, 0, stream>>>(pc, h3b, part, R, 128, (size_t)R * 256);
        statsP_k<256, 4><<<1, 1024, 0, stream>>>(part, g3, b3, st3, 240, 1.f / R);
        scaleB_k<256><<<2048, 256, 0, stream>>>(h3b, st3, H3 / 8);
    }
    // ---- L4 ----  60 m x 8 n x KS4 = 1920 blocks -> combine
    convM_k<256, 512, 4, 6, 10, 3, 5><<<1920, 256, 0, stream>>>(h3b, wB4, h4b, pc, part);
    {
        int R = 512 * 3 * 5;                           // 7680 rows
        combC_k<512, 4><<<240, 256, 0, stream>>>(pc, h4b, part, R, 32, (size_t)R * 512);
        statsP_k<512, 2><<<1, 1024, 0, stream>>>(part, g4, b4, st4, 240, 1.f / R);
    }
    // ---- head (st4 fused) ----
    head_k<<<512, 256, 0, stream>>>(h4b, W5, y, st4, out);
}